// Round 1
// baseline (1749.923 us; speedup 1.0000x reference)
//
#include <hip/hip_runtime.h>

#define D_MODEL 1024
#define HEADS   16
#define HEAD_DIM 64
#define SEQ     2048
#define BATCH   2
#define ROWS    (BATCH*SEQ)   /* 4096 */
#define FFDIM   4096

typedef __attribute__((ext_vector_type(8))) short short8;
typedef __attribute__((ext_vector_type(4))) float f32x4;
typedef __attribute__((ext_vector_type(4))) unsigned short us4;

__device__ __forceinline__ unsigned short f2bf(float f){
  unsigned int x = __float_as_uint(f);
  x += 0x7fffu + ((x >> 16) & 1u);
  return (unsigned short)(x >> 16);
}

__device__ __forceinline__ float wave_max(float x){
  #pragma unroll
  for (int off = 32; off; off >>= 1) x = fmaxf(x, __shfl_xor(x, off));
  return x;
}
__device__ __forceinline__ float wave_sum(float x){
  #pragma unroll
  for (int off = 32; off; off >>= 1) x += __shfl_xor(x, off);
  return x;
}

// ---------------- cast fp32 -> bf16 (vectorized) ----------------
__global__ __launch_bounds__(256) void cast_bf16_kernel(const float* __restrict__ in,
                                                        unsigned short* __restrict__ out, int n4){
  int i = blockIdx.x * 256 + threadIdx.x;
  if (i >= n4) return;
  float4 v = *(const float4*)(in + (size_t)i * 4);
  us4 o;
  o[0] = f2bf(v.x); o[1] = f2bf(v.y); o[2] = f2bf(v.z); o[3] = f2bf(v.w);
  *(us4*)(out + (size_t)i * 4) = o;
}

// ---------------- transpose + cast: in [R][C] f32 -> out [C][R] bf16 ----------------
__global__ __launch_bounds__(256) void transpose_cast_kernel(const float* __restrict__ in,
                                                             unsigned short* __restrict__ out,
                                                             int R, int C){
  __shared__ float tile[32][33];
  const int bc = blockIdx.x * 32, br = blockIdx.y * 32;
  const int tx = threadIdx.x & 31, ty = threadIdx.x >> 5;  // ty 0..7
  #pragma unroll
  for (int j = 0; j < 4; ++j)
    tile[ty + 8*j][tx] = in[(size_t)(br + ty + 8*j) * C + bc + tx];
  __syncthreads();
  #pragma unroll
  for (int j = 0; j < 4; ++j)
    out[(size_t)(bc + ty + 8*j) * R + br + tx] = f2bf(tile[tx][ty + 8*j]);
}

// ---------------- bf16 MFMA GEMM: C[M,N] = A[M,K] * BT[N,K]^T + bias ----------------
// EPI 0: scatter fp32 to q/k/v [B,H,T,64]
// EPI 1: relu -> bf16 row-major
// EPI 2: fp32 row-major
template<int EPI>
__global__ __launch_bounds__(256) void gemm_kernel(const unsigned short* __restrict__ A,
                                                   const unsigned short* __restrict__ BT,
                                                   const float* __restrict__ bias,
                                                   int M, int N, int K,
                                                   float* __restrict__ outF,
                                                   unsigned short* __restrict__ outH,
                                                   float* __restrict__ qo,
                                                   float* __restrict__ ko,
                                                   float* __restrict__ vo){
  __shared__ unsigned short Alds[128 * 40];  // padded stride 40 shorts (80B, 16B-aligned rows)
  __shared__ unsigned short Blds[128 * 40];
  const int tid = threadIdx.x;
  const int lane = tid & 63;
  const int wid = tid >> 6;
  const int wr = wid >> 1, wc = wid & 1;
  const int lrow = lane & 15, lgrp = lane >> 4;
  const int m0 = blockIdx.y * 128, n0 = blockIdx.x * 128;

  f32x4 acc[4][4];
  #pragma unroll
  for (int i = 0; i < 4; ++i)
    #pragma unroll
    for (int j = 0; j < 4; ++j)
      acc[i][j] = f32x4{0.f, 0.f, 0.f, 0.f};

  const int nk = K >> 5;
  for (int kt = 0; kt < nk; ++kt){
    const int kbase = kt * 32;
    __syncthreads();
    #pragma unroll
    for (int it = 0; it < 2; ++it){
      const int idx = tid + it * 256;       // 0..511
      const int r = idx >> 2, ch = idx & 3; // 128 rows x 4 chunks of 8 bf16
      short8 av = *(const short8*)(A  + (size_t)(m0 + r) * K + kbase + ch * 8);
      short8 bv = *(const short8*)(BT + (size_t)(n0 + r) * K + kbase + ch * 8);
      *(short8*)&Alds[r * 40 + ch * 8] = av;
      *(short8*)&Blds[r * 40 + ch * 8] = bv;
    }
    __syncthreads();
    short8 af[4], bf[4];
    #pragma unroll
    for (int f = 0; f < 4; ++f){
      af[f] = *(const short8*)&Alds[(wr * 64 + f * 16 + lrow) * 40 + lgrp * 8];
      bf[f] = *(const short8*)&Blds[(wc * 64 + f * 16 + lrow) * 40 + lgrp * 8];
    }
    #pragma unroll
    for (int i = 0; i < 4; ++i)
      #pragma unroll
      for (int j = 0; j < 4; ++j)
        acc[i][j] = __builtin_amdgcn_mfma_f32_16x16x32_bf16(af[i], bf[j], acc[i][j], 0, 0, 0);
  }

  // epilogue: D row = (lane>>4)*4 + reg, col = lane&15 (m89-verified layout)
  #pragma unroll
  for (int i = 0; i < 4; ++i){
    const int rg = m0 + wr * 64 + i * 16 + lgrp * 4;
    #pragma unroll
    for (int j = 0; j < 4; ++j){
      const int cg = n0 + wc * 64 + j * 16 + lrow;
      const float bb = bias[cg];
      #pragma unroll
      for (int r = 0; r < 4; ++r){
        const int rowg = rg + r;
        const float val = acc[i][j][r] + bb;
        if constexpr (EPI == 0){
          const int which = cg >> 10, rem = cg & 1023;
          const int hh = rem >> 6, dd = rem & 63;
          const int bb_ = rowg >> 11, tt = rowg & 2047;
          float* dst = (which == 0) ? qo : (which == 1) ? ko : vo;
          dst[((size_t)(bb_ * HEADS + hh) * SEQ + tt) * 64 + dd] = val;
        } else if constexpr (EPI == 1){
          outH[(size_t)rowg * N + cg] = f2bf(fmaxf(val, 0.f));
        } else {
          outF[(size_t)rowg * N + cg] = val;
        }
      }
    }
  }
}

// ---------------- flash attention (fp32), causal ----------------
// block = 256 thr (4 waves); handles one (b,h) and 16 query rows r0..r0+15.
// wave w owns rows r0+w+4j, j=0..3. Lanes = keys (phase A) / dims (phase B).
__global__ __launch_bounds__(256) void attn_kernel(const float* __restrict__ Qp,
                                                   const float* __restrict__ Kp,
                                                   const float* __restrict__ Vp,
                                                   float* __restrict__ Op){
  const int tid = threadIdx.x;
  const int w = tid >> 6, lane = tid & 63;
  const int nrg = SEQ / 16;                  // 128
  const int bh = blockIdx.x / nrg;
  const int rg = blockIdx.x % nrg;
  const int r0 = rg * 16;
  const size_t base = (size_t)bh * SEQ * 64;

  __shared__ float KT[64][65];   // transposed: KT[d][k]
  __shared__ float Vs[64][68];   // row-major:  Vs[k][d]
  __shared__ float qs[16][64];   // q rows, pre-scaled by 1/8

  { // load q rows (16 x 64 floats)
    const int r = tid >> 4, c4 = (tid & 15) * 4;
    float4 qv = *(const float4*)(Qp + base + (size_t)(r0 + r) * 64 + c4);
    qs[r][c4 + 0] = qv.x * 0.125f; qs[r][c4 + 1] = qv.y * 0.125f;
    qs[r][c4 + 2] = qv.z * 0.125f; qs[r][c4 + 3] = qv.w * 0.125f;
  }

  float m[4], l[4], o[4];
  #pragma unroll
  for (int j = 0; j < 4; ++j){ m[j] = -INFINITY; l[j] = 0.f; o[j] = 0.f; }

  const int nkb = r0 / 64 + 1;  // covers keys 0..r0+15
  for (int kb = 0; kb < nkb; ++kb){
    const int k0 = kb * 64;
    __syncthreads();
    #pragma unroll
    for (int p = 0; p < 4; ++p){
      const int kr = (tid >> 4) + p * 16;
      const int c4 = (tid & 15) * 4;
      const float4 kvv = *(const float4*)(Kp + base + (size_t)(k0 + kr) * 64 + c4);
      const float4 vvv = *(const float4*)(Vp + base + (size_t)(k0 + kr) * 64 + c4);
      KT[c4 + 0][kr] = kvv.x; KT[c4 + 1][kr] = kvv.y;
      KT[c4 + 2][kr] = kvv.z; KT[c4 + 3][kr] = kvv.w;
      *(float4*)&Vs[kr][c4] = vvv;
    }
    __syncthreads();

    const int key = k0 + lane;
    float s0 = 0.f, s1 = 0.f, s2 = 0.f, s3 = 0.f;
    #pragma unroll 16
    for (int d = 0; d < 64; ++d){
      const float kt = KT[d][lane];
      s0 += qs[w     ][d] * kt;
      s1 += qs[w +  4][d] * kt;
      s2 += qs[w +  8][d] * kt;
      s3 += qs[w + 12][d] * kt;
    }
    float sv[4] = {s0, s1, s2, s3};
    float pv[4];
    #pragma unroll
    for (int j = 0; j < 4; ++j){
      const int rowj = r0 + w + 4 * j;
      const bool ok = key <= rowj;
      const float s = ok ? sv[j] : -INFINITY;
      const float mx = wave_max(s);
      const float mn = fmaxf(m[j], mx);
      const float p = ok ? __expf(s - mn) : 0.f;
      const float sm = wave_sum(p);
      const float corr = __expf(m[j] - mn);
      l[j] = l[j] * corr + sm;
      o[j] *= corr;
      m[j] = mn;
      pv[j] = p;
    }
    #pragma unroll 8
    for (int t = 0; t < 64; ++t){
      const float vt = Vs[t][lane];
      o[0] += __shfl(pv[0], t) * vt;
      o[1] += __shfl(pv[1], t) * vt;
      o[2] += __shfl(pv[2], t) * vt;
      o[3] += __shfl(pv[3], t) * vt;
    }
  }

  const int b = bh >> 4, h = bh & 15;
  #pragma unroll
  for (int j = 0; j < 4; ++j){
    const int rowj = r0 + w + 4 * j;
    Op[((size_t)(b * SEQ) + rowj) * D_MODEL + h * 64 + lane] = o[j] / l[j];
  }
}

// ---------------- fused residual + layernorm ----------------
__global__ __launch_bounds__(256) void ln_kernel(const float* __restrict__ A,
                                                 const float* __restrict__ Badd,
                                                 const float* __restrict__ g,
                                                 const float* __restrict__ be,
                                                 float* __restrict__ outF,
                                                 unsigned short* __restrict__ outH){
  const int row = blockIdx.x, tid = threadIdx.x;
  const size_t base = (size_t)row * D_MODEL + tid * 4;
  float4 va = *(const float4*)(A + base);
  float4 vb = *(const float4*)(Badd + base);
  const float v0 = va.x + vb.x, v1 = va.y + vb.y, v2 = va.z + vb.z, v3 = va.w + vb.w;
  float s  = v0 + v1 + v2 + v3;
  float ss = v0*v0 + v1*v1 + v2*v2 + v3*v3;
  s = wave_sum(s); ss = wave_sum(ss);
  __shared__ float red[8];
  const int w = tid >> 6, lane = tid & 63;
  if (!lane){ red[w] = s; red[4 + w] = ss; }
  __syncthreads();
  s  = red[0] + red[1] + red[2] + red[3];
  ss = red[4] + red[5] + red[6] + red[7];
  const float mu  = s * (1.0f / D_MODEL);
  const float var = ss * (1.0f / D_MODEL) - mu * mu;
  const float rstd = rsqrtf(var + 1e-5f);
  float4 gg = *(const float4*)(g  + tid * 4);
  float4 bb = *(const float4*)(be + tid * 4);
  const float r0 = (v0 - mu) * rstd * gg.x + bb.x;
  const float r1 = (v1 - mu) * rstd * gg.y + bb.y;
  const float r2 = (v2 - mu) * rstd * gg.z + bb.z;
  const float r3 = (v3 - mu) * rstd * gg.w + bb.w;
  float4 of; of.x = r0; of.y = r1; of.z = r2; of.w = r3;
  *(float4*)(outF + base) = of;
  if (outH){
    us4 oh; oh[0] = f2bf(r0); oh[1] = f2bf(r1); oh[2] = f2bf(r2); oh[3] = f2bf(r3);
    *(us4*)(outH + base) = oh;
  }
}

extern "C" void kernel_launch(void* const* d_in, const int* in_sizes, int n_in,
                              void* d_out, int out_size, void* d_ws, size_t ws_size,
                              hipStream_t stream){
  (void)in_sizes; (void)n_in; (void)out_size; (void)ws_size;
  const float* x     = (const float*)d_in[0];
  const float* W_qkv = (const float*)d_in[1];
  const float* b_qkv = (const float*)d_in[2];
  const float* W1    = (const float*)d_in[3];
  const float* b1    = (const float*)d_in[4];
  const float* W2    = (const float*)d_in[5];
  const float* b2    = (const float*)d_in[6];
  const float* ln1g  = (const float*)d_in[7];
  const float* ln1b  = (const float*)d_in[8];
  const float* ln2g  = (const float*)d_in[9];
  const float* ln2b  = (const float*)d_in[10];

  char* ws = (char*)d_ws;
  const size_t MB = 1024ull * 1024ull;
  // layout (with lifetime-safe reuse), total 102 MB:
  unsigned short* WqkvT = (unsigned short*)(ws + 0 * MB);   // [3072][1024] bf16, 6MB
  unsigned short* W1T   = (unsigned short*)(ws + 6 * MB);   // [4096][1024] bf16, 8MB
  unsigned short* W2T   = (unsigned short*)(ws + 14 * MB);  // [1024][4096] bf16, 8MB
  unsigned short* xbf   = (unsigned short*)(ws + 22 * MB);  // [4096][1024] bf16, 8MB
  float* q    = (float*)(ws + 30 * MB);                     // [B,H,T,64] f32, 16MB
  float* k    = (float*)(ws + 46 * MB);                     // 16MB
  float* v    = (float*)(ws + 62 * MB);                     // 16MB
  float* attn = (float*)(ws + 78 * MB);                     // [B,T,C] f32, 16MB
  float* hF           = (float*)(ws + 30 * MB);             // reuse q after attention
  unsigned short* hB  = (unsigned short*)(ws + 46 * MB);    // reuse k
  unsigned short* ff1 = (unsigned short*)(ws + 54 * MB);    // [4096][4096] bf16, 32MB (reuse v+attn)
  float* ff2          = (float*)(ws + 86 * MB);             // [4096][1024] f32, 16MB

  // 1. preprocess: casts + weight transposes
  cast_bf16_kernel<<<4096, 256, 0, stream>>>(x, xbf, ROWS * D_MODEL / 4);
  transpose_cast_kernel<<<dim3(96, 32), 256, 0, stream>>>(W_qkv, WqkvT, 1024, 3072);
  transpose_cast_kernel<<<dim3(128, 32), 256, 0, stream>>>(W1, W1T, 1024, 4096);
  transpose_cast_kernel<<<dim3(32, 128), 256, 0, stream>>>(W2, W2T, 4096, 1024);

  // 2. QKV projection -> q,k,v [B,H,T,64] fp32
  gemm_kernel<0><<<dim3(3072 / 128, ROWS / 128), 256, 0, stream>>>(
      xbf, WqkvT, b_qkv, ROWS, 3072, 1024, nullptr, nullptr, q, k, v);

  // 3. causal flash attention -> attn [B,T,C] fp32
  attn_kernel<<<BATCH * HEADS * (SEQ / 16), 256, 0, stream>>>(q, k, v, attn);

  // 4. h = LN(x + attn) -> hF fp32, hB bf16
  ln_kernel<<<ROWS, 256, 0, stream>>>(x, attn, ln1g, ln1b, hF, hB);

  // 5. ff1 = relu(h @ W1 + b1) -> bf16
  gemm_kernel<1><<<dim3(FFDIM / 128, ROWS / 128), 256, 0, stream>>>(
      hB, W1T, b1, ROWS, FFDIM, 1024, nullptr, ff1, nullptr, nullptr, nullptr);

  // 6. ff2 = ff1 @ W2 + b2 -> fp32
  gemm_kernel<2><<<dim3(1024 / 128, ROWS / 128), 256, 0, stream>>>(
      ff1, W2T, b2, ROWS, 1024, FFDIM, ff2, nullptr, nullptr, nullptr, nullptr);

  // 7. out = LN(h + ff2)
  ln_kernel<<<ROWS, 256, 0, stream>>>(hF, ff2, ln2g, ln2b, (float*)d_out, nullptr);
}

// Round 2
// 452.394 us; speedup vs baseline: 3.8681x; 3.8681x over previous
//
#include <hip/hip_runtime.h>

#define D_MODEL 1024
#define HEADS   16
#define HEAD_DIM 64
#define SEQ     2048
#define BATCH   2
#define ROWS    (BATCH*SEQ)   /* 4096 */
#define FFDIM   4096

typedef __attribute__((ext_vector_type(8))) short short8;
typedef __attribute__((ext_vector_type(4))) float f32x4;
typedef __attribute__((ext_vector_type(4))) unsigned short us4;

__device__ __forceinline__ unsigned short f2bf(float f){
  unsigned int x = __float_as_uint(f);
  x += 0x7fffu + ((x >> 16) & 1u);
  return (unsigned short)(x >> 16);
}

__device__ __forceinline__ float wave_sum(float x){
  #pragma unroll
  for (int off = 32; off; off >>= 1) x += __shfl_xor(x, off);
  return x;
}

// ---------------- cast fp32 -> bf16 (vectorized) ----------------
__global__ __launch_bounds__(256) void cast_bf16_kernel(const float* __restrict__ in,
                                                        unsigned short* __restrict__ out, int n4){
  int i = blockIdx.x * 256 + threadIdx.x;
  if (i >= n4) return;
  float4 v = *(const float4*)(in + (size_t)i * 4);
  us4 o;
  o[0] = f2bf(v.x); o[1] = f2bf(v.y); o[2] = f2bf(v.z); o[3] = f2bf(v.w);
  *(us4*)(out + (size_t)i * 4) = o;
}

// ---------------- transpose + cast: in [R][C] f32 -> out [C][R] bf16 ----------------
__global__ __launch_bounds__(256) void transpose_cast_kernel(const float* __restrict__ in,
                                                             unsigned short* __restrict__ out,
                                                             int R, int C){
  __shared__ float tile[32][33];
  const int bc = blockIdx.x * 32, br = blockIdx.y * 32;
  const int tx = threadIdx.x & 31, ty = threadIdx.x >> 5;  // ty 0..7
  #pragma unroll
  for (int j = 0; j < 4; ++j)
    tile[ty + 8*j][tx] = in[(size_t)(br + ty + 8*j) * C + bc + tx];
  __syncthreads();
  #pragma unroll
  for (int j = 0; j < 4; ++j)
    out[(size_t)(bc + ty + 8*j) * R + br + tx] = f2bf(tile[tx][ty + 8*j]);
}

// ---------------- bf16 MFMA GEMM: C[M,N] = A[M,K] * BT[N,K]^T + bias ----------------
// EPI 0: QKV epilogue -> q bf16 (pre-scaled 1/8) [B,H,T,64], k bf16 [B,H,T,64], V^T bf16 [B,H,64,T]
// EPI 1: relu -> bf16 row-major
// EPI 2: fp32 row-major
template<int EPI>
__global__ __launch_bounds__(256) void gemm_kernel(const unsigned short* __restrict__ A,
                                                   const unsigned short* __restrict__ BT,
                                                   const float* __restrict__ bias,
                                                   int M, int N, int K,
                                                   float* __restrict__ outF,
                                                   unsigned short* __restrict__ outH,
                                                   unsigned short* __restrict__ qo,
                                                   unsigned short* __restrict__ ko,
                                                   unsigned short* __restrict__ vT){
  __shared__ unsigned short Alds[128 * 40];  // padded stride 40 shorts
  __shared__ unsigned short Blds[128 * 40];
  const int tid = threadIdx.x;
  const int lane = tid & 63;
  const int wid = tid >> 6;
  const int wr = wid >> 1, wc = wid & 1;
  const int lrow = lane & 15, lgrp = lane >> 4;
  const int m0 = blockIdx.y * 128, n0 = blockIdx.x * 128;

  f32x4 acc[4][4];
  #pragma unroll
  for (int i = 0; i < 4; ++i)
    #pragma unroll
    for (int j = 0; j < 4; ++j)
      acc[i][j] = f32x4{0.f, 0.f, 0.f, 0.f};

  const int nk = K >> 5;
  for (int kt = 0; kt < nk; ++kt){
    const int kbase = kt * 32;
    __syncthreads();
    #pragma unroll
    for (int it = 0; it < 2; ++it){
      const int idx = tid + it * 256;       // 0..511
      const int r = idx >> 2, ch = idx & 3; // 128 rows x 4 chunks of 8 bf16
      short8 av = *(const short8*)(A  + (size_t)(m0 + r) * K + kbase + ch * 8);
      short8 bv = *(const short8*)(BT + (size_t)(n0 + r) * K + kbase + ch * 8);
      *(short8*)&Alds[r * 40 + ch * 8] = av;
      *(short8*)&Blds[r * 40 + ch * 8] = bv;
    }
    __syncthreads();
    short8 af[4], bfr[4];
    #pragma unroll
    for (int f = 0; f < 4; ++f){
      af[f]  = *(const short8*)&Alds[(wr * 64 + f * 16 + lrow) * 40 + lgrp * 8];
      bfr[f] = *(const short8*)&Blds[(wc * 64 + f * 16 + lrow) * 40 + lgrp * 8];
    }
    #pragma unroll
    for (int i = 0; i < 4; ++i)
      #pragma unroll
      for (int j = 0; j < 4; ++j)
        acc[i][j] = __builtin_amdgcn_mfma_f32_16x16x32_bf16(af[i], bfr[j], acc[i][j], 0, 0, 0);
  }

  // epilogue: D row = (lane>>4)*4 + reg, col = lane&15 (m89-verified layout)
  #pragma unroll
  for (int i = 0; i < 4; ++i){
    const int rg = m0 + wr * 64 + i * 16 + lgrp * 4;   // multiple of 4
    #pragma unroll
    for (int j = 0; j < 4; ++j){
      const int cg = n0 + wc * 64 + j * 16 + lrow;
      const float bb = bias[cg];
      if constexpr (EPI == 0){
        const int which = cg >> 10, rem = cg & 1023;
        const int hh = rem >> 6, dd = rem & 63;
        const int bb_ = rg >> 11, tt = rg & 2047;
        const size_t bh = (size_t)(bb_ * HEADS + hh);
        if (which == 2){
          us4 pk;
          #pragma unroll
          for (int r = 0; r < 4; ++r) pk[r] = f2bf(acc[i][j][r] + bb);
          *(us4*)(vT + (bh * 64 + dd) * SEQ + tt) = pk;
        } else {
          unsigned short* dst = which ? ko : qo;
          const float sc = which ? 1.0f : 0.125f;
          #pragma unroll
          for (int r = 0; r < 4; ++r)
            dst[(bh * SEQ + tt + r) * 64 + dd] = f2bf((acc[i][j][r] + bb) * sc);
        }
      } else {
        #pragma unroll
        for (int r = 0; r < 4; ++r){
          const float val = acc[i][j][r] + bb;
          if constexpr (EPI == 1){
            outH[(size_t)(rg + r) * N + cg] = f2bf(fmaxf(val, 0.f));
          } else {
            outF[(size_t)(rg + r) * N + cg] = val;
          }
        }
      }
    }
  }
}

// ---------------- MFMA flash attention (bf16 in, fp32 out), causal ----------------
// grid: (qb 0..31 reversed, bh 0..31); block = 4 independent waves, each owns 16 query rows.
// Swapped QK^T: S^T = mfma(K_frag, Q_frag) so each lane holds one query row's keys in-register.
__global__ __launch_bounds__(256) void attn_mfma_kernel(const unsigned short* __restrict__ Qb,
                                                        const unsigned short* __restrict__ Kb,
                                                        const unsigned short* __restrict__ VT,
                                                        float* __restrict__ Op){
  __shared__ __align__(16) char Plds[4 * 2048];   // per-wave 16x64 bf16, XOR-swizzled
  const int tid  = threadIdx.x;
  const int w    = tid >> 6, lane = tid & 63;
  const int lr   = lane & 15, g = lane >> 4;      // lr = query col / frag row; g = lane group
  const int qb   = 31 - blockIdx.x;               // longest blocks first
  const int bh   = blockIdx.y;
  const int q0   = qb * 64 + w * 16;
  const int qglob = q0 + lr;
  char* const pbase = Plds + w * 2048;

  // Q fragments (B-operand): lane reads Q[q0+lr][g*8 .. +7] for each 32-d chunk
  const unsigned short* qrow = Qb + ((size_t)bh * SEQ + q0 + lr) * 64 + g * 8;
  const short8 qf0 = *(const short8*)(qrow);
  const short8 qf1 = *(const short8*)(qrow + 32);

  f32x4 o[4];
  #pragma unroll
  for (int dt = 0; dt < 4; ++dt) o[dt] = f32x4{0.f, 0.f, 0.f, 0.f};
  float m = -INFINITY, l = 0.f;

  const int swz = (lr & 7) << 4;

  for (int kb = 0; kb <= qb; ++kb){
    const int k0 = kb * 64;

    // ---- S^T = K * Q^T : 4 key-tiles x 2 d-chunks ----
    f32x4 s[4];
    #pragma unroll
    for (int kt = 0; kt < 4; ++kt){
      const unsigned short* krow = Kb + ((size_t)bh * SEQ + k0 + kt * 16 + lr) * 64 + g * 8;
      const short8 kf0 = *(const short8*)(krow);
      const short8 kf1 = *(const short8*)(krow + 32);
      s[kt] = __builtin_amdgcn_mfma_f32_16x16x32_bf16(kf0, qf0, f32x4{0.f,0.f,0.f,0.f}, 0, 0, 0);
      s[kt] = __builtin_amdgcn_mfma_f32_16x16x32_bf16(kf1, qf1, s[kt], 0, 0, 0);
    }

    // causal mask (only the diagonal block needs it)
    if (kb == qb){
      #pragma unroll
      for (int kt = 0; kt < 4; ++kt)
        #pragma unroll
        for (int r = 0; r < 4; ++r)
          if (k0 + kt * 16 + g * 4 + r > qglob) s[kt][r] = -INFINITY;
    }

    // ---- online softmax: row = query (lane holds 16 of the row's 64 keys) ----
    float mx = -INFINITY;
    #pragma unroll
    for (int kt = 0; kt < 4; ++kt)
      #pragma unroll
      for (int r = 0; r < 4; ++r) mx = fmaxf(mx, s[kt][r]);
    mx = fmaxf(mx, __shfl_xor(mx, 16));
    mx = fmaxf(mx, __shfl_xor(mx, 32));
    const float mn = fmaxf(m, mx);
    const float corr = __expf(m - mn);
    float sum = 0.f;
    #pragma unroll
    for (int kt = 0; kt < 4; ++kt)
      #pragma unroll
      for (int r = 0; r < 4; ++r){
        const float p = __expf(s[kt][r] - mn);
        s[kt][r] = p;
        sum += p;
      }
    sum += __shfl_xor(sum, 16);
    sum += __shfl_xor(sum, 32);
    l = l * corr + sum;
    m = mn;

    // ---- P -> bf16 -> swizzled LDS (row = query lr, col = key) ----
    #pragma unroll
    for (int kt = 0; kt < 4; ++kt){
      us4 pk;
      #pragma unroll
      for (int r = 0; r < 4; ++r) pk[r] = f2bf(s[kt][r]);
      *(us4*)(pbase + lr * 128 + ((kt * 32 + g * 8) ^ swz)) = pk;
    }

    // rescale existing output (out-acc rows are queries g*4+r; fetch their corr)
    float oc[4];
    #pragma unroll
    for (int r = 0; r < 4; ++r) oc[r] = __shfl(corr, g * 4 + r);
    #pragma unroll
    for (int dt = 0; dt < 4; ++dt)
      #pragma unroll
      for (int r = 0; r < 4; ++r) o[dt][r] *= oc[r];

    // ---- PV: A = P (from LDS), B = V^T rows (global, L2-resident) ----
    const short8 pa0 = *(const short8*)(pbase + lr * 128 + ((0 * 64 + g * 16) ^ swz));
    const short8 pa1 = *(const short8*)(pbase + lr * 128 + ((1 * 64 + g * 16) ^ swz));
    #pragma unroll
    for (int dt = 0; dt < 4; ++dt){
      const unsigned short* vrow = VT + ((size_t)bh * 64 + dt * 16 + lr) * SEQ + k0 + g * 8;
      const short8 vf0 = *(const short8*)(vrow);
      const short8 vf1 = *(const short8*)(vrow + 32);
      o[dt] = __builtin_amdgcn_mfma_f32_16x16x32_bf16(pa0, vf0, o[dt], 0, 0, 0);
      o[dt] = __builtin_amdgcn_mfma_f32_16x16x32_bf16(pa1, vf1, o[dt], 0, 0, 0);
    }
  }

  // ---- finalize: divide by l (per out-row query), store [B,T,C] fp32 ----
  float lr_[4];
  #pragma unroll
  for (int r = 0; r < 4; ++r) lr_[r] = __shfl(l, g * 4 + r);
  const int b = bh >> 4, h = bh & 15;
  #pragma unroll
  for (int dt = 0; dt < 4; ++dt)
    #pragma unroll
    for (int r = 0; r < 4; ++r)
      Op[((size_t)(b * SEQ) + q0 + g * 4 + r) * D_MODEL + h * 64 + dt * 16 + lr] = o[dt][r] / lr_[r];
}

// ---------------- fused residual + layernorm ----------------
__global__ __launch_bounds__(256) void ln_kernel(const float* __restrict__ A,
                                                 const float* __restrict__ Badd,
                                                 const float* __restrict__ g,
                                                 const float* __restrict__ be,
                                                 float* __restrict__ outF,
                                                 unsigned short* __restrict__ outH){
  const int row = blockIdx.x, tid = threadIdx.x;
  const size_t base = (size_t)row * D_MODEL + tid * 4;
  float4 va = *(const float4*)(A + base);
  float4 vb = *(const float4*)(Badd + base);
  const float v0 = va.x + vb.x, v1 = va.y + vb.y, v2 = va.z + vb.z, v3 = va.w + vb.w;
  float s  = v0 + v1 + v2 + v3;
  float ss = v0*v0 + v1*v1 + v2*v2 + v3*v3;
  s = wave_sum(s); ss = wave_sum(ss);
  __shared__ float red[8];
  const int w = tid >> 6, lane = tid & 63;
  if (!lane){ red[w] = s; red[4 + w] = ss; }
  __syncthreads();
  s  = red[0] + red[1] + red[2] + red[3];
  ss = red[4] + red[5] + red[6] + red[7];
  const float mu  = s * (1.0f / D_MODEL);
  const float var = ss * (1.0f / D_MODEL) - mu * mu;
  const float rstd = rsqrtf(var + 1e-5f);
  float4 gg = *(const float4*)(g  + tid * 4);
  float4 bb = *(const float4*)(be + tid * 4);
  const float r0 = (v0 - mu) * rstd * gg.x + bb.x;
  const float r1 = (v1 - mu) * rstd * gg.y + bb.y;
  const float r2 = (v2 - mu) * rstd * gg.z + bb.z;
  const float r3 = (v3 - mu) * rstd * gg.w + bb.w;
  float4 of; of.x = r0; of.y = r1; of.z = r2; of.w = r3;
  *(float4*)(outF + base) = of;
  if (outH){
    us4 oh; oh[0] = f2bf(r0); oh[1] = f2bf(r1); oh[2] = f2bf(r2); oh[3] = f2bf(r3);
    *(us4*)(outH + base) = oh;
  }
}

extern "C" void kernel_launch(void* const* d_in, const int* in_sizes, int n_in,
                              void* d_out, int out_size, void* d_ws, size_t ws_size,
                              hipStream_t stream){
  (void)in_sizes; (void)n_in; (void)out_size; (void)ws_size;
  const float* x     = (const float*)d_in[0];
  const float* W_qkv = (const float*)d_in[1];
  const float* b_qkv = (const float*)d_in[2];
  const float* W1    = (const float*)d_in[3];
  const float* b1    = (const float*)d_in[4];
  const float* W2    = (const float*)d_in[5];
  const float* b2    = (const float*)d_in[6];
  const float* ln1g  = (const float*)d_in[7];
  const float* ln1b  = (const float*)d_in[8];
  const float* ln2g  = (const float*)d_in[9];
  const float* ln2b  = (const float*)d_in[10];

  char* ws = (char*)d_ws;
  const size_t MB = 1024ull * 1024ull;
  // layout (lifetime-safe reuse):
  unsigned short* WqkvT = (unsigned short*)(ws + 0 * MB);   // [3072][1024] bf16, 6MB
  unsigned short* W1T   = (unsigned short*)(ws + 6 * MB);   // [4096][1024] bf16, 8MB
  unsigned short* W2T   = (unsigned short*)(ws + 14 * MB);  // [1024][4096] bf16, 8MB
  unsigned short* xbf   = (unsigned short*)(ws + 22 * MB);  // [4096][1024] bf16, 8MB
  unsigned short* qB    = (unsigned short*)(ws + 30 * MB);  // [B,H,T,64] bf16 (pre-scaled), 8.4MB
  unsigned short* kB    = (unsigned short*)(ws + 39 * MB);  // [B,H,T,64] bf16, 8.4MB
  unsigned short* vT    = (unsigned short*)(ws + 48 * MB);  // [B,H,64,T] bf16, 8.4MB
  float* attn = (float*)(ws + 57 * MB);                     // [B,T,C] f32, 16MB
  float* hF           = (float*)(ws + 30 * MB);             // reuse qB/kB region after attention
  unsigned short* hB  = (unsigned short*)(ws + 46 * MB);    // 8MB (dead kB/vT region)
  unsigned short* ff1 = (unsigned short*)(ws + 54 * MB);    // [4096][4096] bf16, 32MB (dead vT/attn)
  float* ff2          = (float*)(ws + 86 * MB);             // [4096][1024] f32, 16MB

  // 1. preprocess: casts + weight transposes
  cast_bf16_kernel<<<4096, 256, 0, stream>>>(x, xbf, ROWS * D_MODEL / 4);
  transpose_cast_kernel<<<dim3(96, 32), 256, 0, stream>>>(W_qkv, WqkvT, 1024, 3072);
  transpose_cast_kernel<<<dim3(128, 32), 256, 0, stream>>>(W1, W1T, 1024, 4096);
  transpose_cast_kernel<<<dim3(32, 128), 256, 0, stream>>>(W2, W2T, 4096, 1024);

  // 2. QKV projection -> qB (scaled), kB, vT (all bf16)
  gemm_kernel<0><<<dim3(3072 / 128, ROWS / 128), 256, 0, stream>>>(
      xbf, WqkvT, b_qkv, ROWS, 3072, 1024, nullptr, nullptr, qB, kB, vT);

  // 3. causal MFMA flash attention -> attn [B,T,C] fp32
  attn_mfma_kernel<<<dim3(32, 32), 256, 0, stream>>>(qB, kB, vT, attn);

  // 4. h = LN(x + attn) -> hF fp32, hB bf16
  ln_kernel<<<ROWS, 256, 0, stream>>>(x, attn, ln1g, ln1b, hF, hB);

  // 5. ff1 = relu(h @ W1 + b1) -> bf16
  gemm_kernel<1><<<dim3(FFDIM / 128, ROWS / 128), 256, 0, stream>>>(
      hB, W1T, b1, ROWS, FFDIM, 1024, nullptr, ff1, nullptr, nullptr, nullptr);

  // 6. ff2 = ff1 @ W2 + b2 -> fp32
  gemm_kernel<2><<<dim3(1024 / 128, ROWS / 128), 256, 0, stream>>>(
      ff1, W2T, b2, ROWS, 1024, FFDIM, ff2, nullptr, nullptr, nullptr, nullptr);

  // 7. out = LN(h + ff2)
  ln_kernel<<<ROWS, 256, 0, stream>>>(hF, ff2, ln2g, ln2b, (float*)d_out, nullptr);
}

// Round 3
// 451.490 us; speedup vs baseline: 3.8759x; 1.0020x over previous
//
#include <hip/hip_runtime.h>

#define D_MODEL 1024
#define HEADS   16
#define HEAD_DIM 64
#define SEQ     2048
#define BATCH   2
#define ROWS    (BATCH*SEQ)   /* 4096 */
#define FFDIM   4096

typedef __attribute__((ext_vector_type(8))) short short8;
typedef __attribute__((ext_vector_type(4))) float f32x4;
typedef __attribute__((ext_vector_type(4))) unsigned short us4;

typedef const __attribute__((address_space(1))) unsigned int* gptr_t;
typedef __attribute__((address_space(3))) unsigned int* lptr_t;

__device__ __forceinline__ unsigned short f2bf(float f){
  unsigned int x = __float_as_uint(f);
  x += 0x7fffu + ((x >> 16) & 1u);
  return (unsigned short)(x >> 16);
}

__device__ __forceinline__ float wave_sum(float x){
  #pragma unroll
  for (int off = 32; off; off >>= 1) x += __shfl_xor(x, off);
  return x;
}

// ---------------- cast fp32 -> bf16 (vectorized) ----------------
__global__ __launch_bounds__(256) void cast_bf16_kernel(const float* __restrict__ in,
                                                        unsigned short* __restrict__ out, int n4){
  int i = blockIdx.x * 256 + threadIdx.x;
  if (i >= n4) return;
  float4 v = *(const float4*)(in + (size_t)i * 4);
  us4 o;
  o[0] = f2bf(v.x); o[1] = f2bf(v.y); o[2] = f2bf(v.z); o[3] = f2bf(v.w);
  *(us4*)(out + (size_t)i * 4) = o;
}

// ---------------- transpose + cast: in [R][C] f32 -> out [C][R] bf16 ----------------
__global__ __launch_bounds__(256) void transpose_cast_kernel(const float* __restrict__ in,
                                                             unsigned short* __restrict__ out,
                                                             int R, int C){
  __shared__ float tile[32][33];
  const int bc = blockIdx.x * 32, br = blockIdx.y * 32;
  const int tx = threadIdx.x & 31, ty = threadIdx.x >> 5;  // ty 0..7
  #pragma unroll
  for (int j = 0; j < 4; ++j)
    tile[ty + 8*j][tx] = in[(size_t)(br + ty + 8*j) * C + bc + tx];
  __syncthreads();
  #pragma unroll
  for (int j = 0; j < 4; ++j)
    out[(size_t)(bc + ty + 8*j) * R + br + tx] = f2bf(tile[tx][ty + 8*j]);
}

// ---------------- bf16 MFMA GEMM (m97 structure): C = A[M,K] * BT[N,K]^T + bias ----------------
// global_load_lds width=16 into linear [128][32] LDS tiles.
// EPI 0: QKV epilogue -> q bf16 (pre-scaled 1/8) [B,H,T,64], k bf16 [B,H,T,64], V^T bf16 [B,H,64,T]
// EPI 1: relu -> bf16 row-major
// EPI 2: fp32 row-major
template<int EPI>
__global__ __launch_bounds__(256) void gemm_kernel(const unsigned short* __restrict__ A,
                                                   const unsigned short* __restrict__ BT,
                                                   const float* __restrict__ bias,
                                                   int M, int N, int K,
                                                   float* __restrict__ outF,
                                                   unsigned short* __restrict__ outH,
                                                   unsigned short* __restrict__ qo,
                                                   unsigned short* __restrict__ ko,
                                                   unsigned short* __restrict__ vT){
  __shared__ __align__(16) unsigned short Alds[128 * 32];
  __shared__ __align__(16) unsigned short Blds[128 * 32];
  const int tid = threadIdx.x;
  const int lane = tid & 63;
  const int wid = tid >> 6;
  const int wr = wid >> 1, wc = wid & 1;
  const int lrow = lane & 15, lgrp = lane >> 4;
  const int m0 = blockIdx.y * 128, n0 = blockIdx.x * 128;

  // staging geometry: chunk = 16 rows x 32 shorts = 1KB; wave handles chunks wid*2, wid*2+1;
  // lane l deposits 16B at lds chunkbase + l*16 == row (l>>2), col (l&3)*8 (linear row-major)
  const int sr = lane >> 2, sc = (lane & 3) * 8;

  f32x4 acc[4][4];
  #pragma unroll
  for (int i = 0; i < 4; ++i)
    #pragma unroll
    for (int j = 0; j < 4; ++j)
      acc[i][j] = f32x4{0.f, 0.f, 0.f, 0.f};

  const int nk = K >> 5;
  for (int kt = 0; kt < nk; ++kt){
    const int kbase = kt * 32;
    __syncthreads();
    #pragma unroll
    for (int it = 0; it < 2; ++it){
      const int c = wid * 2 + it;
      const int r = c * 16 + sr;
      __builtin_amdgcn_global_load_lds(
          (gptr_t)(const void*)(A + (size_t)(m0 + r) * K + kbase + sc),
          (lptr_t)(void*)(&Alds[c * 512]), 16, 0, 0);
      __builtin_amdgcn_global_load_lds(
          (gptr_t)(const void*)(BT + (size_t)(n0 + r) * K + kbase + sc),
          (lptr_t)(void*)(&Blds[c * 512]), 16, 0, 0);
    }
    __syncthreads();
    short8 af[4], bfr[4];
    #pragma unroll
    for (int f = 0; f < 4; ++f){
      af[f]  = *(const short8*)&Alds[(wr * 64 + f * 16 + lrow) * 32 + lgrp * 8];
      bfr[f] = *(const short8*)&Blds[(wc * 64 + f * 16 + lrow) * 32 + lgrp * 8];
    }
    #pragma unroll
    for (int i = 0; i < 4; ++i)
      #pragma unroll
      for (int j = 0; j < 4; ++j)
        acc[i][j] = __builtin_amdgcn_mfma_f32_16x16x32_bf16(af[i], bfr[j], acc[i][j], 0, 0, 0);
  }

  // epilogue: D row = (lane>>4)*4 + reg, col = lane&15 (m89-verified layout)
  #pragma unroll
  for (int i = 0; i < 4; ++i){
    const int rg = m0 + wr * 64 + i * 16 + lgrp * 4;   // multiple of 4
    #pragma unroll
    for (int j = 0; j < 4; ++j){
      const int cg = n0 + wc * 64 + j * 16 + lrow;
      const float bb = bias[cg];
      if constexpr (EPI == 0){
        const int which = cg >> 10, rem = cg & 1023;
        const int hh = rem >> 6, dd = rem & 63;
        const int bb_ = rg >> 11, tt = rg & 2047;
        const size_t bh = (size_t)(bb_ * HEADS + hh);
        if (which == 2){
          us4 pk;
          #pragma unroll
          for (int r = 0; r < 4; ++r) pk[r] = f2bf(acc[i][j][r] + bb);
          *(us4*)(vT + (bh * 64 + dd) * SEQ + tt) = pk;
        } else {
          unsigned short* dst = which ? ko : qo;
          const float sc2 = which ? 1.0f : 0.125f;
          #pragma unroll
          for (int r = 0; r < 4; ++r)
            dst[(bh * SEQ + tt + r) * 64 + dd] = f2bf((acc[i][j][r] + bb) * sc2);
        }
      } else {
        #pragma unroll
        for (int r = 0; r < 4; ++r){
          const float val = acc[i][j][r] + bb;
          if constexpr (EPI == 1){
            outH[(size_t)(rg + r) * N + cg] = f2bf(fmaxf(val, 0.f));
          } else {
            outF[(size_t)(rg + r) * N + cg] = val;
          }
        }
      }
    }
  }
}

// ---------------- MFMA flash attention (bf16 in, fp32 out), causal ----------------
// grid: (qb 0..31 reversed, bh 0..31); 4 independent waves/block, each owns 16 query rows.
// Swapped QK^T (S^T = mfma(K,Q)); V issued early + K register-prefetched one block ahead.
__global__ __launch_bounds__(256) void attn_mfma_kernel(const unsigned short* __restrict__ Qb,
                                                        const unsigned short* __restrict__ Kb,
                                                        const unsigned short* __restrict__ VT,
                                                        float* __restrict__ Op){
  __shared__ __align__(16) char Plds[4 * 2048];   // per-wave 16x64 bf16, XOR-swizzled
  const int tid  = threadIdx.x;
  const int w    = tid >> 6, lane = tid & 63;
  const int lr   = lane & 15, g = lane >> 4;
  const int qb   = 31 - blockIdx.x;               // longest blocks first
  const int bh   = blockIdx.y;
  const int q0   = qb * 64 + w * 16;
  const int qglob = q0 + lr;
  char* const pbase = Plds + w * 2048;

  const unsigned short* const Kbh = Kb + (size_t)bh * SEQ * 64;
  const unsigned short* const Vbh = VT + (size_t)bh * 64 * SEQ;

  // Q fragments (B-operand): lane reads Q[q0+lr][g*8 .. +7] per 32-d chunk
  const unsigned short* qrow = Qb + ((size_t)bh * SEQ + q0 + lr) * 64 + g * 8;
  const short8 qf0 = *(const short8*)(qrow);
  const short8 qf1 = *(const short8*)(qrow + 32);

  f32x4 o[4];
  #pragma unroll
  for (int dt = 0; dt < 4; ++dt) o[dt] = f32x4{0.f, 0.f, 0.f, 0.f};
  float m = -INFINITY, l = 0.f;
  const int swz = (lr & 7) << 4;

  // preload K block 0
  short8 kc[4][2];
  #pragma unroll
  for (int kt = 0; kt < 4; ++kt){
    const unsigned short* krow = Kbh + (size_t)(kt * 16 + lr) * 64 + g * 8;
    kc[kt][0] = *(const short8*)(krow);
    kc[kt][1] = *(const short8*)(krow + 32);
  }

  int kb = 0;
  while (true){
    const int k0 = kb * 64;
    const bool last = (kb == qb);

    // ---- issue V loads for this block early (latency hides under QK+softmax) ----
    short8 vf[4][2];
    #pragma unroll
    for (int dt = 0; dt < 4; ++dt){
      const unsigned short* vrow = Vbh + (size_t)(dt * 16 + lr) * SEQ + k0 + g * 8;
      vf[dt][0] = *(const short8*)(vrow);
      vf[dt][1] = *(const short8*)(vrow + 32);
    }

    // ---- S^T = K * Q^T ----
    f32x4 s[4];
    __builtin_amdgcn_s_setprio(1);
    #pragma unroll
    for (int kt = 0; kt < 4; ++kt){
      s[kt] = __builtin_amdgcn_mfma_f32_16x16x32_bf16(kc[kt][0], qf0, f32x4{0.f,0.f,0.f,0.f}, 0, 0, 0);
      s[kt] = __builtin_amdgcn_mfma_f32_16x16x32_bf16(kc[kt][1], qf1, s[kt], 0, 0, 0);
    }
    __builtin_amdgcn_s_setprio(0);

    // ---- prefetch next K block (latency hides under softmax+PV) ----
    short8 kn[4][2];
    if (!last){
      #pragma unroll
      for (int kt = 0; kt < 4; ++kt){
        const unsigned short* krow = Kbh + (size_t)(k0 + 64 + kt * 16 + lr) * 64 + g * 8;
        kn[kt][0] = *(const short8*)(krow);
        kn[kt][1] = *(const short8*)(krow + 32);
      }
    }

    // causal mask (diagonal block only)
    if (last){
      #pragma unroll
      for (int kt = 0; kt < 4; ++kt)
        #pragma unroll
        for (int r = 0; r < 4; ++r)
          if (k0 + kt * 16 + g * 4 + r > qglob) s[kt][r] = -INFINITY;
    }

    // ---- online softmax (row = query lr; lane holds 16 of its 64 keys) ----
    float mx = -INFINITY;
    #pragma unroll
    for (int kt = 0; kt < 4; ++kt)
      #pragma unroll
      for (int r = 0; r < 4; ++r) mx = fmaxf(mx, s[kt][r]);
    mx = fmaxf(mx, __shfl_xor(mx, 16));
    mx = fmaxf(mx, __shfl_xor(mx, 32));
    const float mn = fmaxf(m, mx);
    const float corr = __expf(m - mn);
    float sum = 0.f;
    #pragma unroll
    for (int kt = 0; kt < 4; ++kt)
      #pragma unroll
      for (int r = 0; r < 4; ++r){
        const float p = __expf(s[kt][r] - mn);
        s[kt][r] = p;
        sum += p;
      }
    sum += __shfl_xor(sum, 16);
    sum += __shfl_xor(sum, 32);
    l = l * corr + sum;
    m = mn;

    // ---- P -> bf16 -> swizzled LDS (row = query lr, col = key) ----
    #pragma unroll
    for (int kt = 0; kt < 4; ++kt){
      us4 pk;
      #pragma unroll
      for (int r = 0; r < 4; ++r) pk[r] = f2bf(s[kt][r]);
      *(us4*)(pbase + lr * 128 + ((kt * 32 + g * 8) ^ swz)) = pk;
    }

    // rescale existing output (out-acc rows are queries g*4+r)
    float oc[4];
    #pragma unroll
    for (int r = 0; r < 4; ++r) oc[r] = __shfl(corr, g * 4 + r);
    #pragma unroll
    for (int dt = 0; dt < 4; ++dt)
      #pragma unroll
      for (int r = 0; r < 4; ++r) o[dt][r] *= oc[r];

    // ---- PV: A = P (LDS), B = V^T rows (regs, loaded early) ----
    const short8 pa0 = *(const short8*)(pbase + lr * 128 + ((0 * 64 + g * 16) ^ swz));
    const short8 pa1 = *(const short8*)(pbase + lr * 128 + ((1 * 64 + g * 16) ^ swz));
    __builtin_amdgcn_s_setprio(1);
    #pragma unroll
    for (int dt = 0; dt < 4; ++dt){
      o[dt] = __builtin_amdgcn_mfma_f32_16x16x32_bf16(pa0, vf[dt][0], o[dt], 0, 0, 0);
      o[dt] = __builtin_amdgcn_mfma_f32_16x16x32_bf16(pa1, vf[dt][1], o[dt], 0, 0, 0);
    }
    __builtin_amdgcn_s_setprio(0);

    if (last) break;
    #pragma unroll
    for (int kt = 0; kt < 4; ++kt){ kc[kt][0] = kn[kt][0]; kc[kt][1] = kn[kt][1]; }
    ++kb;
  }

  // ---- finalize: divide by l (per out-row query), store [B,T,C] fp32 ----
  float lr_[4];
  #pragma unroll
  for (int r = 0; r < 4; ++r) lr_[r] = __shfl(l, g * 4 + r);
  const int b = bh >> 4, h = bh & 15;
  #pragma unroll
  for (int dt = 0; dt < 4; ++dt)
    #pragma unroll
    for (int r = 0; r < 4; ++r)
      Op[((size_t)(b * SEQ) + q0 + g * 4 + r) * D_MODEL + h * 64 + dt * 16 + lr] = o[dt][r] / lr_[r];
}

// ---------------- fused residual + layernorm ----------------
__global__ __launch_bounds__(256) void ln_kernel(const float* __restrict__ A,
                                                 const float* __restrict__ Badd,
                                                 const float* __restrict__ g,
                                                 const float* __restrict__ be,
                                                 float* __restrict__ outF,
                                                 unsigned short* __restrict__ outH){
  const int row = blockIdx.x, tid = threadIdx.x;
  const size_t base = (size_t)row * D_MODEL + tid * 4;
  float4 va = *(const float4*)(A + base);
  float4 vb = *(const float4*)(Badd + base);
  const float v0 = va.x + vb.x, v1 = va.y + vb.y, v2 = va.z + vb.z, v3 = va.w + vb.w;
  float s  = v0 + v1 + v2 + v3;
  float ss = v0*v0 + v1*v1 + v2*v2 + v3*v3;
  s = wave_sum(s); ss = wave_sum(ss);
  __shared__ float red[8];
  const int w = tid >> 6, lane = tid & 63;
  if (!lane){ red[w] = s; red[4 + w] = ss; }
  __syncthreads();
  s  = red[0] + red[1] + red[2] + red[3];
  ss = red[4] + red[5] + red[6] + red[7];
  const float mu  = s * (1.0f / D_MODEL);
  const float var = ss * (1.0f / D_MODEL) - mu * mu;
  const float rstd = rsqrtf(var + 1e-5f);
  float4 gg = *(const float4*)(g  + tid * 4);
  float4 bb = *(const float4*)(be + tid * 4);
  const float r0 = (v0 - mu) * rstd * gg.x + bb.x;
  const float r1 = (v1 - mu) * rstd * gg.y + bb.y;
  const float r2 = (v2 - mu) * rstd * gg.z + bb.z;
  const float r3 = (v3 - mu) * rstd * gg.w + bb.w;
  float4 of; of.x = r0; of.y = r1; of.z = r2; of.w = r3;
  *(float4*)(outF + base) = of;
  if (outH){
    us4 oh; oh[0] = f2bf(r0); oh[1] = f2bf(r1); oh[2] = f2bf(r2); oh[3] = f2bf(r3);
    *(us4*)(outH + base) = oh;
  }
}

extern "C" void kernel_launch(void* const* d_in, const int* in_sizes, int n_in,
                              void* d_out, int out_size, void* d_ws, size_t ws_size,
                              hipStream_t stream){
  (void)in_sizes; (void)n_in; (void)out_size; (void)ws_size;
  const float* x     = (const float*)d_in[0];
  const float* W_qkv = (const float*)d_in[1];
  const float* b_qkv = (const float*)d_in[2];
  const float* W1    = (const float*)d_in[3];
  const float* b1    = (const float*)d_in[4];
  const float* W2    = (const float*)d_in[5];
  const float* b2    = (const float*)d_in[6];
  const float* ln1g  = (const float*)d_in[7];
  const float* ln1b  = (const float*)d_in[8];
  const float* ln2g  = (const float*)d_in[9];
  const float* ln2b  = (const float*)d_in[10];

  char* ws = (char*)d_ws;
  const size_t MB = 1024ull * 1024ull;
  unsigned short* WqkvT = (unsigned short*)(ws + 0 * MB);   // [3072][1024] bf16, 6MB
  unsigned short* W1T   = (unsigned short*)(ws + 6 * MB);   // [4096][1024] bf16, 8MB
  unsigned short* W2T   = (unsigned short*)(ws + 14 * MB);  // [1024][4096] bf16, 8MB
  unsigned short* xbf   = (unsigned short*)(ws + 22 * MB);  // [4096][1024] bf16, 8MB
  unsigned short* qB    = (unsigned short*)(ws + 30 * MB);  // [B,H,T,64] bf16 (pre-scaled), 8.4MB
  unsigned short* kB    = (unsigned short*)(ws + 39 * MB);  // [B,H,T,64] bf16, 8.4MB
  unsigned short* vT    = (unsigned short*)(ws + 48 * MB);  // [B,H,64,T] bf16, 8.4MB
  float* attn = (float*)(ws + 57 * MB);                     // [B,T,C] f32, 16MB
  float* hF           = (float*)(ws + 30 * MB);             // reuse qB/kB region after attention
  unsigned short* hB  = (unsigned short*)(ws + 46 * MB);    // 8MB (dead kB/vT region)
  unsigned short* ff1 = (unsigned short*)(ws + 54 * MB);    // [4096][4096] bf16, 32MB (dead vT/attn)
  float* ff2          = (float*)(ws + 86 * MB);             // [4096][1024] f32, 16MB

  // 1. preprocess: casts + weight transposes
  cast_bf16_kernel<<<4096, 256, 0, stream>>>(x, xbf, ROWS * D_MODEL / 4);
  transpose_cast_kernel<<<dim3(96, 32), 256, 0, stream>>>(W_qkv, WqkvT, 1024, 3072);
  transpose_cast_kernel<<<dim3(128, 32), 256, 0, stream>>>(W1, W1T, 1024, 4096);
  transpose_cast_kernel<<<dim3(32, 128), 256, 0, stream>>>(W2, W2T, 4096, 1024);

  // 2. QKV projection -> qB (scaled), kB, vT (all bf16)
  gemm_kernel<0><<<dim3(3072 / 128, ROWS / 128), 256, 0, stream>>>(
      xbf, WqkvT, b_qkv, ROWS, 3072, 1024, nullptr, nullptr, qB, kB, vT);

  // 3. causal MFMA flash attention -> attn [B,T,C] fp32
  attn_mfma_kernel<<<dim3(32, 32), 256, 0, stream>>>(qB, kB, vT, attn);

  // 4. h = LN(x + attn) -> hF fp32, hB bf16
  ln_kernel<<<ROWS, 256, 0, stream>>>(x, attn, ln1g, ln1b, hF, hB);

  // 5. ff1 = relu(h @ W1 + b1) -> bf16
  gemm_kernel<1><<<dim3(FFDIM / 128, ROWS / 128), 256, 0, stream>>>(
      hB, W1T, b1, ROWS, FFDIM, 1024, nullptr, ff1, nullptr, nullptr, nullptr);

  // 6. ff2 = ff1 @ W2 + b2 -> fp32
  gemm_kernel<2><<<dim3(1024 / 128, ROWS / 128), 256, 0, stream>>>(
      ff1, W2T, b2, ROWS, 1024, FFDIM, ff2, nullptr, nullptr, nullptr, nullptr);

  // 7. out = LN(h + ff2)
  ln_kernel<<<ROWS, 256, 0, stream>>>(hF, ff2, ln2g, ln2b, (float*)d_out, nullptr);
}

// Round 4
// 450.033 us; speedup vs baseline: 3.8884x; 1.0032x over previous
//
#include <hip/hip_runtime.h>

#define D_MODEL 1024
#define HEADS   16
#define HEAD_DIM 64
#define SEQ     2048
#define BATCH   2
#define ROWS    (BATCH*SEQ)   /* 4096 */
#define FFDIM   4096

typedef __attribute__((ext_vector_type(8))) short short8;
typedef __attribute__((ext_vector_type(4))) float f32x4;
typedef __attribute__((ext_vector_type(4))) unsigned short us4;

typedef const __attribute__((address_space(1))) unsigned int* gptr_t;
typedef __attribute__((address_space(3))) unsigned int* lptr_t;

__device__ __forceinline__ unsigned short f2bf(float f){
  unsigned int x = __float_as_uint(f);
  x += 0x7fffu + ((x >> 16) & 1u);
  return (unsigned short)(x >> 16);
}

__device__ __forceinline__ float wave_sum(float x){
  #pragma unroll
  for (int off = 32; off; off >>= 1) x += __shfl_xor(x, off);
  return x;
}

// ---------------- cast fp32 -> bf16 (vectorized) ----------------
__global__ __launch_bounds__(256) void cast_bf16_kernel(const float* __restrict__ in,
                                                        unsigned short* __restrict__ out, int n4){
  int i = blockIdx.x * 256 + threadIdx.x;
  if (i >= n4) return;
  float4 v = *(const float4*)(in + (size_t)i * 4);
  us4 o;
  o[0] = f2bf(v.x); o[1] = f2bf(v.y); o[2] = f2bf(v.z); o[3] = f2bf(v.w);
  *(us4*)(out + (size_t)i * 4) = o;
}

// ---------------- transpose + cast: in [R][C] f32 -> out [C][R] bf16 ----------------
__global__ __launch_bounds__(256) void transpose_cast_kernel(const float* __restrict__ in,
                                                             unsigned short* __restrict__ out,
                                                             int R, int C){
  __shared__ float tile[32][33];
  const int bc = blockIdx.x * 32, br = blockIdx.y * 32;
  const int tx = threadIdx.x & 31, ty = threadIdx.x >> 5;  // ty 0..7
  #pragma unroll
  for (int j = 0; j < 4; ++j)
    tile[ty + 8*j][tx] = in[(size_t)(br + ty + 8*j) * C + bc + tx];
  __syncthreads();
  #pragma unroll
  for (int j = 0; j < 4; ++j)
    out[(size_t)(bc + ty + 8*j) * R + br + tx] = f2bf(tile[tx][ty + 8*j]);
}

// ---------------- bf16 MFMA GEMM (m97 structure): C = A[M,K] * BT[N,K]^T + bias ----------------
// global_load_lds width=16 into linear [128][32] LDS tiles.
// EPI 0: QKV epilogue -> q bf16 (pre-scaled 1/8) [B,H,T,64], k bf16 [B,H,T,64], V^T bf16 [B,H,64,T]
// EPI 1: relu -> bf16 row-major
// EPI 2: fp32 row-major
template<int EPI>
__global__ __launch_bounds__(256) void gemm_kernel(const unsigned short* __restrict__ A,
                                                   const unsigned short* __restrict__ BT,
                                                   const float* __restrict__ bias,
                                                   int M, int N, int K,
                                                   float* __restrict__ outF,
                                                   unsigned short* __restrict__ outH,
                                                   unsigned short* __restrict__ qo,
                                                   unsigned short* __restrict__ ko,
                                                   unsigned short* __restrict__ vT){
  __shared__ __align__(16) unsigned short Alds[128 * 32];
  __shared__ __align__(16) unsigned short Blds[128 * 32];
  const int tid = threadIdx.x;
  const int lane = tid & 63;
  const int wid = tid >> 6;
  const int wr = wid >> 1, wc = wid & 1;
  const int lrow = lane & 15, lgrp = lane >> 4;
  const int m0 = blockIdx.y * 128, n0 = blockIdx.x * 128;

  const int sr = lane >> 2, sc = (lane & 3) * 8;

  f32x4 acc[4][4];
  #pragma unroll
  for (int i = 0; i < 4; ++i)
    #pragma unroll
    for (int j = 0; j < 4; ++j)
      acc[i][j] = f32x4{0.f, 0.f, 0.f, 0.f};

  const int nk = K >> 5;
  for (int kt = 0; kt < nk; ++kt){
    const int kbase = kt * 32;
    __syncthreads();
    #pragma unroll
    for (int it = 0; it < 2; ++it){
      const int c = wid * 2 + it;
      const int r = c * 16 + sr;
      __builtin_amdgcn_global_load_lds(
          (gptr_t)(const void*)(A + (size_t)(m0 + r) * K + kbase + sc),
          (lptr_t)(void*)(&Alds[c * 512]), 16, 0, 0);
      __builtin_amdgcn_global_load_lds(
          (gptr_t)(const void*)(BT + (size_t)(n0 + r) * K + kbase + sc),
          (lptr_t)(void*)(&Blds[c * 512]), 16, 0, 0);
    }
    __syncthreads();
    short8 af[4], bfr[4];
    #pragma unroll
    for (int f = 0; f < 4; ++f){
      af[f]  = *(const short8*)&Alds[(wr * 64 + f * 16 + lrow) * 32 + lgrp * 8];
      bfr[f] = *(const short8*)&Blds[(wc * 64 + f * 16 + lrow) * 32 + lgrp * 8];
    }
    #pragma unroll
    for (int i = 0; i < 4; ++i)
      #pragma unroll
      for (int j = 0; j < 4; ++j)
        acc[i][j] = __builtin_amdgcn_mfma_f32_16x16x32_bf16(af[i], bfr[j], acc[i][j], 0, 0, 0);
  }

  // epilogue: D row = (lane>>4)*4 + reg, col = lane&15 (m89-verified layout)
  #pragma unroll
  for (int i = 0; i < 4; ++i){
    const int rg = m0 + wr * 64 + i * 16 + lgrp * 4;   // multiple of 4
    #pragma unroll
    for (int j = 0; j < 4; ++j){
      const int cg = n0 + wc * 64 + j * 16 + lrow;
      const float bb = bias[cg];
      if constexpr (EPI == 0){
        const int which = cg >> 10, rem = cg & 1023;
        const int hh = rem >> 6, dd = rem & 63;
        const int bb_ = rg >> 11, tt = rg & 2047;
        const size_t bh = (size_t)(bb_ * HEADS + hh);
        if (which == 2){
          us4 pk;
          #pragma unroll
          for (int r = 0; r < 4; ++r) pk[r] = f2bf(acc[i][j][r] + bb);
          *(us4*)(vT + (bh * 64 + dd) * SEQ + tt) = pk;
        } else {
          unsigned short* dst = which ? ko : qo;
          const float sc2 = which ? 1.0f : 0.125f;
          #pragma unroll
          for (int r = 0; r < 4; ++r)
            dst[(bh * SEQ + tt + r) * 64 + dd] = f2bf((acc[i][j][r] + bb) * sc2);
        }
      } else {
        #pragma unroll
        for (int r = 0; r < 4; ++r){
          const float val = acc[i][j][r] + bb;
          if constexpr (EPI == 1){
            outH[(size_t)(rg + r) * N + cg] = f2bf(fmaxf(val, 0.f));
          } else {
            outF[(size_t)(rg + r) * N + cg] = val;
          }
        }
      }
    }
  }
}

// ---------------- MFMA flash attention (bf16 in, fp32 out), causal ----------------
// grid: (qg 0..63 reversed, bh 0..31); 128 threads = 2 INDEPENDENT waves, each owns 16 query rows.
// No __syncthreads: each wave runs its own exact trip count (fine-grained load balance).
// Swapped QK^T (S^T = mfma(K,Q)) so each lane holds one query row's keys in-register.
__global__ __launch_bounds__(128) void attn_mfma_kernel(const unsigned short* __restrict__ Qb,
                                                        const unsigned short* __restrict__ Kb,
                                                        const unsigned short* __restrict__ VT,
                                                        float* __restrict__ Op){
  __shared__ __align__(16) char Plds[2 * 2048];   // per-wave 16x64 bf16, XOR-swizzled
  const int tid  = threadIdx.x;
  const int w    = tid >> 6, lane = tid & 63;
  const int lr   = lane & 15, g = lane >> 4;
  const int qg   = 63 - blockIdx.x;               // longest blocks first
  const int bh   = blockIdx.y;
  const int q0   = qg * 32 + w * 16;
  const int qglob = q0 + lr;
  char* const pbase = Plds + w * 2048;

  const unsigned short* const Kbh = Kb + (size_t)bh * SEQ * 64;
  const unsigned short* const Vbh = VT + (size_t)bh * 64 * SEQ;

  // Q fragments (B-operand): lane reads Q[q0+lr][g*8 .. +7] per 32-d chunk
  const unsigned short* qrow = Qb + ((size_t)bh * SEQ + q0 + lr) * 64 + g * 8;
  const short8 qf0 = *(const short8*)(qrow);
  const short8 qf1 = *(const short8*)(qrow + 32);

  f32x4 o[4];
  #pragma unroll
  for (int dt = 0; dt < 4; ++dt) o[dt] = f32x4{0.f, 0.f, 0.f, 0.f};
  float m = -INFINITY, l = 0.f;
  const int swz = (lr & 7) << 4;

  const int kbmax = (q0 + 15) >> 6;   // per-wave trip count
  for (int kb = 0; kb <= kbmax; ++kb){
    const int k0 = kb * 64;

    // ---- S^T = K * Q^T : 4 key-tiles x 2 d-chunks ----
    f32x4 s[4];
    __builtin_amdgcn_s_setprio(1);
    #pragma unroll
    for (int kt = 0; kt < 4; ++kt){
      const unsigned short* krow = Kbh + (size_t)(k0 + kt * 16 + lr) * 64 + g * 8;
      const short8 kf0 = *(const short8*)(krow);
      const short8 kf1 = *(const short8*)(krow + 32);
      s[kt] = __builtin_amdgcn_mfma_f32_16x16x32_bf16(kf0, qf0, f32x4{0.f,0.f,0.f,0.f}, 0, 0, 0);
      s[kt] = __builtin_amdgcn_mfma_f32_16x16x32_bf16(kf1, qf1, s[kt], 0, 0, 0);
    }
    __builtin_amdgcn_s_setprio(0);

    // causal mask (last block only)
    if (kb == kbmax){
      #pragma unroll
      for (int kt = 0; kt < 4; ++kt)
        #pragma unroll
        for (int r = 0; r < 4; ++r)
          if (k0 + kt * 16 + g * 4 + r > qglob) s[kt][r] = -INFINITY;
    }

    // ---- online softmax (row = query lr; lane holds 16 of its 64 keys) ----
    float mx = -INFINITY;
    #pragma unroll
    for (int kt = 0; kt < 4; ++kt)
      #pragma unroll
      for (int r = 0; r < 4; ++r) mx = fmaxf(mx, s[kt][r]);
    mx = fmaxf(mx, __shfl_xor(mx, 16));
    mx = fmaxf(mx, __shfl_xor(mx, 32));
    const float mn = fmaxf(m, mx);
    const float corr = __expf(m - mn);
    float sum = 0.f;
    #pragma unroll
    for (int kt = 0; kt < 4; ++kt)
      #pragma unroll
      for (int r = 0; r < 4; ++r){
        const float p = __expf(s[kt][r] - mn);
        s[kt][r] = p;
        sum += p;
      }
    sum += __shfl_xor(sum, 16);
    sum += __shfl_xor(sum, 32);
    l = l * corr + sum;
    m = mn;

    // ---- P -> bf16 -> swizzled LDS (row = query lr, col = key) ----
    #pragma unroll
    for (int kt = 0; kt < 4; ++kt){
      us4 pk;
      #pragma unroll
      for (int r = 0; r < 4; ++r) pk[r] = f2bf(s[kt][r]);
      *(us4*)(pbase + lr * 128 + ((kt * 32 + g * 8) ^ swz)) = pk;
    }

    // rescale existing output (out-acc rows are queries g*4+r)
    float oc[4];
    #pragma unroll
    for (int r = 0; r < 4; ++r) oc[r] = __shfl(corr, g * 4 + r);
    #pragma unroll
    for (int dt = 0; dt < 4; ++dt)
      #pragma unroll
      for (int r = 0; r < 4; ++r) o[dt][r] *= oc[r];

    // ---- PV: A = P (LDS), B = V^T rows (global, L2-resident) ----
    const short8 pa0 = *(const short8*)(pbase + lr * 128 + ((0 * 64 + g * 16) ^ swz));
    const short8 pa1 = *(const short8*)(pbase + lr * 128 + ((1 * 64 + g * 16) ^ swz));
    __builtin_amdgcn_s_setprio(1);
    #pragma unroll
    for (int dt = 0; dt < 4; ++dt){
      const unsigned short* vrow = Vbh + (size_t)(dt * 16 + lr) * SEQ + k0 + g * 8;
      const short8 vf0 = *(const short8*)(vrow);
      const short8 vf1 = *(const short8*)(vrow + 32);
      o[dt] = __builtin_amdgcn_mfma_f32_16x16x32_bf16(pa0, vf0, o[dt], 0, 0, 0);
      o[dt] = __builtin_amdgcn_mfma_f32_16x16x32_bf16(pa1, vf1, o[dt], 0, 0, 0);
    }
    __builtin_amdgcn_s_setprio(0);
  }

  // ---- finalize: divide by l (per out-row query), store [B,T,C] fp32 ----
  float lr_[4];
  #pragma unroll
  for (int r = 0; r < 4; ++r) lr_[r] = __shfl(l, g * 4 + r);
  const int b = bh >> 4, h = bh & 15;
  #pragma unroll
  for (int dt = 0; dt < 4; ++dt)
    #pragma unroll
    for (int r = 0; r < 4; ++r)
      Op[((size_t)(b * SEQ) + q0 + g * 4 + r) * D_MODEL + h * 64 + dt * 16 + lr] = o[dt][r] / lr_[r];
}

// ---------------- fused residual + layernorm ----------------
__global__ __launch_bounds__(256) void ln_kernel(const float* __restrict__ A,
                                                 const float* __restrict__ Badd,
                                                 const float* __restrict__ g,
                                                 const float* __restrict__ be,
                                                 float* __restrict__ outF,
                                                 unsigned short* __restrict__ outH){
  const int row = blockIdx.x, tid = threadIdx.x;
  const size_t base = (size_t)row * D_MODEL + tid * 4;
  float4 va = *(const float4*)(A + base);
  float4 vb = *(const float4*)(Badd + base);
  const float v0 = va.x + vb.x, v1 = va.y + vb.y, v2 = va.z + vb.z, v3 = va.w + vb.w;
  float s  = v0 + v1 + v2 + v3;
  float ss = v0*v0 + v1*v1 + v2*v2 + v3*v3;
  s = wave_sum(s); ss = wave_sum(ss);
  __shared__ float red[8];
  const int w = tid >> 6, lane = tid & 63;
  if (!lane){ red[w] = s; red[4 + w] = ss; }
  __syncthreads();
  s  = red[0] + red[1] + red[2] + red[3];
  ss = red[4] + red[5] + red[6] + red[7];
  const float mu  = s * (1.0f / D_MODEL);
  const float var = ss * (1.0f / D_MODEL) - mu * mu;
  const float rstd = rsqrtf(var + 1e-5f);
  float4 gg = *(const float4*)(g  + tid * 4);
  float4 bb = *(const float4*)(be + tid * 4);
  const float r0 = (v0 - mu) * rstd * gg.x + bb.x;
  const float r1 = (v1 - mu) * rstd * gg.y + bb.y;
  const float r2 = (v2 - mu) * rstd * gg.z + bb.z;
  const float r3 = (v3 - mu) * rstd * gg.w + bb.w;
  float4 of; of.x = r0; of.y = r1; of.z = r2; of.w = r3;
  *(float4*)(outF + base) = of;
  if (outH){
    us4 oh; oh[0] = f2bf(r0); oh[1] = f2bf(r1); oh[2] = f2bf(r2); oh[3] = f2bf(r3);
    *(us4*)(outH + base) = oh;
  }
}

extern "C" void kernel_launch(void* const* d_in, const int* in_sizes, int n_in,
                              void* d_out, int out_size, void* d_ws, size_t ws_size,
                              hipStream_t stream){
  (void)in_sizes; (void)n_in; (void)out_size; (void)ws_size;
  const float* x     = (const float*)d_in[0];
  const float* W_qkv = (const float*)d_in[1];
  const float* b_qkv = (const float*)d_in[2];
  const float* W1    = (const float*)d_in[3];
  const float* b1    = (const float*)d_in[4];
  const float* W2    = (const float*)d_in[5];
  const float* b2    = (const float*)d_in[6];
  const float* ln1g  = (const float*)d_in[7];
  const float* ln1b  = (const float*)d_in[8];
  const float* ln2g  = (const float*)d_in[9];
  const float* ln2b  = (const float*)d_in[10];

  char* ws = (char*)d_ws;
  const size_t MB = 1024ull * 1024ull;
  unsigned short* WqkvT = (unsigned short*)(ws + 0 * MB);   // [3072][1024] bf16, 6MB
  unsigned short* W1T   = (unsigned short*)(ws + 6 * MB);   // [4096][1024] bf16, 8MB
  unsigned short* W2T   = (unsigned short*)(ws + 14 * MB);  // [1024][4096] bf16, 8MB
  unsigned short* xbf   = (unsigned short*)(ws + 22 * MB);  // [4096][1024] bf16, 8MB
  unsigned short* qB    = (unsigned short*)(ws + 30 * MB);  // [B,H,T,64] bf16 (pre-scaled), 8.4MB
  unsigned short* kB    = (unsigned short*)(ws + 39 * MB);  // [B,H,T,64] bf16, 8.4MB
  unsigned short* vT    = (unsigned short*)(ws + 48 * MB);  // [B,H,64,T] bf16, 8.4MB
  float* attn = (float*)(ws + 57 * MB);                     // [B,T,C] f32, 16MB
  float* hF           = (float*)(ws + 30 * MB);             // reuse qB/kB region after attention
  unsigned short* hB  = (unsigned short*)(ws + 46 * MB);    // 8MB (dead kB/vT region)
  unsigned short* ff1 = (unsigned short*)(ws + 54 * MB);    // [4096][4096] bf16, 32MB (dead vT/attn)
  float* ff2          = (float*)(ws + 86 * MB);             // [4096][1024] f32, 16MB

  // 1. preprocess: casts + weight transposes
  cast_bf16_kernel<<<4096, 256, 0, stream>>>(x, xbf, ROWS * D_MODEL / 4);
  transpose_cast_kernel<<<dim3(96, 32), 256, 0, stream>>>(W_qkv, WqkvT, 1024, 3072);
  transpose_cast_kernel<<<dim3(128, 32), 256, 0, stream>>>(W1, W1T, 1024, 4096);
  transpose_cast_kernel<<<dim3(32, 128), 256, 0, stream>>>(W2, W2T, 4096, 1024);

  // 2. QKV projection -> qB (scaled), kB, vT (all bf16)
  gemm_kernel<0><<<dim3(3072 / 128, ROWS / 128), 256, 0, stream>>>(
      xbf, WqkvT, b_qkv, ROWS, 3072, 1024, nullptr, nullptr, qB, kB, vT);

  // 3. causal MFMA flash attention -> attn [B,T,C] fp32
  attn_mfma_kernel<<<dim3(64, 32), 128, 0, stream>>>(qB, kB, vT, attn);

  // 4. h = LN(x + attn) -> hF fp32, hB bf16
  ln_kernel<<<ROWS, 256, 0, stream>>>(x, attn, ln1g, ln1b, hF, hB);

  // 5. ff1 = relu(h @ W1 + b1) -> bf16
  gemm_kernel<1><<<dim3(FFDIM / 128, ROWS / 128), 256, 0, stream>>>(
      hB, W1T, b1, ROWS, FFDIM, 1024, nullptr, ff1, nullptr, nullptr, nullptr);

  // 6. ff2 = ff1 @ W2 + b2 -> fp32
  gemm_kernel<2><<<dim3(1024 / 128, ROWS / 128), 256, 0, stream>>>(
      ff1, W2T, b2, ROWS, 1024, FFDIM, ff2, nullptr, nullptr, nullptr, nullptr);

  // 7. out = LN(h + ff2)
  ln_kernel<<<ROWS, 256, 0, stream>>>(hF, ff2, ln2g, ln2b, (float*)d_out, nullptr);
}

// Round 5
// 283.529 us; speedup vs baseline: 6.1719x; 1.5873x over previous
//
#include <hip/hip_runtime.h>

#define D_MODEL 1024
#define HEADS   16
#define HEAD_DIM 64
#define SEQ     2048
#define BATCH   2
#define ROWS    (BATCH*SEQ)   /* 4096 */
#define FFDIM   4096

typedef __attribute__((ext_vector_type(8))) short short8;
typedef __attribute__((ext_vector_type(4))) float f32x4;
typedef __attribute__((ext_vector_type(4))) unsigned short us4;

typedef const __attribute__((address_space(1))) unsigned int* gptr_t;
typedef __attribute__((address_space(3))) unsigned int* lptr_t;

__device__ __forceinline__ unsigned short f2bf(float f){
  unsigned int x = __float_as_uint(f);
  x += 0x7fffu + ((x >> 16) & 1u);
  return (unsigned short)(x >> 16);
}

__device__ __forceinline__ float wave_sum(float x){
  #pragma unroll
  for (int off = 32; off; off >>= 1) x += __shfl_xor(x, off);
  return x;
}

// ---------------- cast fp32 -> bf16 (vectorized) ----------------
__global__ __launch_bounds__(256) void cast_bf16_kernel(const float* __restrict__ in,
                                                        unsigned short* __restrict__ out, int n4){
  int i = blockIdx.x * 256 + threadIdx.x;
  if (i >= n4) return;
  float4 v = *(const float4*)(in + (size_t)i * 4);
  us4 o;
  o[0] = f2bf(v.x); o[1] = f2bf(v.y); o[2] = f2bf(v.z); o[3] = f2bf(v.w);
  *(us4*)(out + (size_t)i * 4) = o;
}

// ---------------- transpose + cast: in [R][C] f32 -> out [C][R] bf16 ----------------
__global__ __launch_bounds__(256) void transpose_cast_kernel(const float* __restrict__ in,
                                                             unsigned short* __restrict__ out,
                                                             int R, int C){
  __shared__ float tile[32][33];
  const int bc = blockIdx.x * 32, br = blockIdx.y * 32;
  const int tx = threadIdx.x & 31, ty = threadIdx.x >> 5;  // ty 0..7
  #pragma unroll
  for (int j = 0; j < 4; ++j)
    tile[ty + 8*j][tx] = in[(size_t)(br + ty + 8*j) * C + bc + tx];
  __syncthreads();
  #pragma unroll
  for (int j = 0; j < 4; ++j)
    out[(size_t)(bc + ty + 8*j) * R + br + tx] = f2bf(tile[tx][ty + 8*j]);
}

// ---------------- bf16 MFMA GEMM (m97 structure): C = A[M,K] * BT[N,K]^T + bias ----------------
template<int EPI>
__global__ __launch_bounds__(256) void gemm_kernel(const unsigned short* __restrict__ A,
                                                   const unsigned short* __restrict__ BT,
                                                   const float* __restrict__ bias,
                                                   int M, int N, int K,
                                                   float* __restrict__ outF,
                                                   unsigned short* __restrict__ outH,
                                                   unsigned short* __restrict__ qo,
                                                   unsigned short* __restrict__ ko,
                                                   unsigned short* __restrict__ vT){
  __shared__ __align__(16) unsigned short Alds[128 * 32];
  __shared__ __align__(16) unsigned short Blds[128 * 32];
  const int tid = threadIdx.x;
  const int lane = tid & 63;
  const int wid = tid >> 6;
  const int wr = wid >> 1, wc = wid & 1;
  const int lrow = lane & 15, lgrp = lane >> 4;
  const int m0 = blockIdx.y * 128, n0 = blockIdx.x * 128;

  const int sr = lane >> 2, sc = (lane & 3) * 8;

  f32x4 acc[4][4];
  #pragma unroll
  for (int i = 0; i < 4; ++i)
    #pragma unroll
    for (int j = 0; j < 4; ++j)
      acc[i][j] = f32x4{0.f, 0.f, 0.f, 0.f};

  const int nk = K >> 5;
  for (int kt = 0; kt < nk; ++kt){
    const int kbase = kt * 32;
    __syncthreads();
    #pragma unroll
    for (int it = 0; it < 2; ++it){
      const int c = wid * 2 + it;
      const int r = c * 16 + sr;
      __builtin_amdgcn_global_load_lds(
          (gptr_t)(const void*)(A + (size_t)(m0 + r) * K + kbase + sc),
          (lptr_t)(void*)(&Alds[c * 512]), 16, 0, 0);
      __builtin_amdgcn_global_load_lds(
          (gptr_t)(const void*)(BT + (size_t)(n0 + r) * K + kbase + sc),
          (lptr_t)(void*)(&Blds[c * 512]), 16, 0, 0);
    }
    __syncthreads();
    short8 af[4], bfr[4];
    #pragma unroll
    for (int f = 0; f < 4; ++f){
      af[f]  = *(const short8*)&Alds[(wr * 64 + f * 16 + lrow) * 32 + lgrp * 8];
      bfr[f] = *(const short8*)&Blds[(wc * 64 + f * 16 + lrow) * 32 + lgrp * 8];
    }
    #pragma unroll
    for (int i = 0; i < 4; ++i)
      #pragma unroll
      for (int j = 0; j < 4; ++j)
        acc[i][j] = __builtin_amdgcn_mfma_f32_16x16x32_bf16(af[i], bfr[j], acc[i][j], 0, 0, 0);
  }

  // epilogue: D row = (lane>>4)*4 + reg, col = lane&15 (m89-verified layout)
  #pragma unroll
  for (int i = 0; i < 4; ++i){
    const int rg = m0 + wr * 64 + i * 16 + lgrp * 4;   // multiple of 4
    #pragma unroll
    for (int j = 0; j < 4; ++j){
      const int cg = n0 + wc * 64 + j * 16 + lrow;
      const float bb = bias[cg];
      if constexpr (EPI == 0){
        const int which = cg >> 10, rem = cg & 1023;
        const int hh = rem >> 6, dd = rem & 63;
        const int bb_ = rg >> 11, tt = rg & 2047;
        const size_t bh = (size_t)(bb_ * HEADS + hh);
        if (which == 2){
          us4 pk;
          #pragma unroll
          for (int r = 0; r < 4; ++r) pk[r] = f2bf(acc[i][j][r] + bb);
          *(us4*)(vT + (bh * 64 + dd) * SEQ + tt) = pk;
        } else {
          unsigned short* dst = which ? ko : qo;
          const float sc2 = which ? 1.0f : 0.125f;
          #pragma unroll
          for (int r = 0; r < 4; ++r)
            dst[(bh * SEQ + tt + r) * 64 + dd] = f2bf((acc[i][j][r] + bb) * sc2);
        }
      } else {
        #pragma unroll
        for (int r = 0; r < 4; ++r){
          const float val = acc[i][j][r] + bb;
          if constexpr (EPI == 1){
            outH[(size_t)(rg + r) * N + cg] = f2bf(fmaxf(val, 0.f));
          } else {
            outF[(size_t)(rg + r) * N + cg] = val;
          }
        }
      }
    }
  }
}

// ---------------- MFMA flash attention v2: LDS-shared K/V tiles, causal ----------------
// 512 blocks x 256 thr. Block = 4 waves x 32 query rows = 128 rows of one (b,h).
// K-tile [64k][64d] + V^T-tile [64d][64k] staged in XOR-swizzled LDS once per k-step,
// double-buffered, 2-phase pipeline (prefetch never crosses a barrier unconsumed).
// Each wave computes 2 swapped-QK S-tiles (rows lr and lr+16) per K-fragment read.
__global__ __launch_bounds__(256) void attn_mfma_kernel(const unsigned short* __restrict__ Qb,
                                                        const unsigned short* __restrict__ Kb,
                                                        const unsigned short* __restrict__ VT,
                                                        float* __restrict__ Op){
  __shared__ __align__(16) char Kl[2][8192];
  __shared__ __align__(16) char Vl[2][8192];
  __shared__ __align__(16) char Pl[4][4096];
  const int tid = threadIdx.x;
  const int w = tid >> 6, lane = tid & 63;
  const int lr = lane & 15, g = lane >> 4;

  // block index map: pair (f, f+256) -> (15-g8, g8): constant trip sum per CU slot;
  // bh%8 == blockIdx%8 -> 4 heads per XCD (K/V working set ~= L2 size)
  const int bx = blockIdx.x, u = bx & 255, half = bx >> 8;
  const int g8 = u >> 5;
  const int qg = half ? g8 : 15 - g8;
  const int bh = u & 31;

  const int q0w = qg * 128 + w * 32;
  const int qA = q0w + lr, qB = qA + 16;

  const char* const KbB = (const char*)(Kb + (size_t)bh * SEQ * 64);
  const char* const VbB = (const char*)(VT + (size_t)bh * 64 * SEQ);
  char* const PbA = Pl[w];
  char* const PbB = Pl[w] + 2048;

  // Q fragments (B-operand), two row-sets
  const unsigned short* qra = Qb + ((size_t)bh * SEQ + qA) * 64 + g * 8;
  const short8 qfA0 = *(const short8*)(qra);
  const short8 qfA1 = *(const short8*)(qra + 32);
  const short8 qfB0 = *(const short8*)(qra + 16 * 64);
  const short8 qfB1 = *(const short8*)(qra + 16 * 64 + 32);

  f32x4 oA[4], oB[4];
  #pragma unroll
  for (int dt = 0; dt < 4; ++dt){ oA[dt] = f32x4{0.f,0.f,0.f,0.f}; oB[dt] = f32x4{0.f,0.f,0.f,0.f}; }
  float mA = -INFINITY, lA = 0.f, mB = -INFINITY, lB = 0.f;
  const int swzl = (lr & 7) << 4;

  const int kbmax = 2 * qg + 1;

  // staging: thread stages 2x16B of K-tile + 2x16B of V-tile per k-step
  short8 st[4];
  {
    #pragma unroll
    for (int c = 0; c < 2; ++c){
      const int L = c * 4096 + tid * 16;
      st[c] = *(const short8*)(KbB + L);                       // tile0: k0=0
      const int row = L >> 7, col = L & 127;
      st[2 + c] = *(const short8*)(VbB + (size_t)row * 4096 + col);
    }
  }

  for (int kb = 0; kb <= kbmax; ++kb){
    const int p = kb & 1;
    const int k0 = kb * 64;

    // ---- write staged tile (waits vmcnt for st) ----
    #pragma unroll
    for (int c = 0; c < 2; ++c){
      const int L = c * 4096 + tid * 16;
      const int row = L >> 7, col = L & 127;
      const int dst = row * 128 + (col ^ ((row & 7) << 4));
      *(short8*)(Kl[p] + dst) = st[c];
      *(short8*)(Vl[p] + dst) = st[2 + c];
    }
    __syncthreads();

    // ---- issue next-tile loads (in flight during compute; consumed next iter) ----
    if (kb < kbmax){
      #pragma unroll
      for (int c = 0; c < 2; ++c){
        const int L = c * 4096 + tid * 16;
        st[c] = *(const short8*)(KbB + (size_t)(kb + 1) * 8192 + L);
        const int row = L >> 7, col = L & 127;
        st[2 + c] = *(const short8*)(VbB + (size_t)row * 4096 + (size_t)(kb + 1) * 128 + col);
      }
    }

    // ---- S^T = K * Q^T for both row-sets (K fragment read once) ----
    f32x4 sA[4], sB[4];
    __builtin_amdgcn_s_setprio(1);
    #pragma unroll
    for (int kt = 0; kt < 4; ++kt){
      const int row = kt * 16 + lr;
      const int ro = row * 128, sw = (row & 7) << 4;
      const short8 kf0 = *(const short8*)(Kl[p] + ro + ((g * 16) ^ sw));
      const short8 kf1 = *(const short8*)(Kl[p] + ro + ((64 + g * 16) ^ sw));
      sA[kt] = __builtin_amdgcn_mfma_f32_16x16x32_bf16(kf0, qfA0, f32x4{0.f,0.f,0.f,0.f}, 0, 0, 0);
      sA[kt] = __builtin_amdgcn_mfma_f32_16x16x32_bf16(kf1, qfA1, sA[kt], 0, 0, 0);
      sB[kt] = __builtin_amdgcn_mfma_f32_16x16x32_bf16(kf0, qfB0, f32x4{0.f,0.f,0.f,0.f}, 0, 0, 0);
      sB[kt] = __builtin_amdgcn_mfma_f32_16x16x32_bf16(kf1, qfB1, sB[kt], 0, 0, 0);
    }
    __builtin_amdgcn_s_setprio(0);

    // ---- causal mask (only the last two k-steps can touch the diagonal) ----
    if (kb >= kbmax - 1){
      #pragma unroll
      for (int kt = 0; kt < 4; ++kt)
        #pragma unroll
        for (int r = 0; r < 4; ++r){
          const int key = k0 + kt * 16 + g * 4 + r;
          if (key > qA) sA[kt][r] = -INFINITY;
          if (key > qB) sB[kt][r] = -INFINITY;
        }
    }

    // ---- online softmax + P write, set A ----
    {
      float mx = -INFINITY;
      #pragma unroll
      for (int kt = 0; kt < 4; ++kt)
        #pragma unroll
        for (int r = 0; r < 4; ++r) mx = fmaxf(mx, sA[kt][r]);
      mx = fmaxf(mx, __shfl_xor(mx, 16));
      mx = fmaxf(mx, __shfl_xor(mx, 32));
      const float mn = fmaxf(mA, mx);
      const float corr = __expf(mA - mn);
      float sum = 0.f;
      #pragma unroll
      for (int kt = 0; kt < 4; ++kt)
        #pragma unroll
        for (int r = 0; r < 4; ++r){
          const float pp = __expf(sA[kt][r] - mn);
          sA[kt][r] = pp; sum += pp;
        }
      sum += __shfl_xor(sum, 16);
      sum += __shfl_xor(sum, 32);
      lA = lA * corr + sum; mA = mn;
      #pragma unroll
      for (int kt = 0; kt < 4; ++kt){
        us4 pk;
        #pragma unroll
        for (int r = 0; r < 4; ++r) pk[r] = f2bf(sA[kt][r]);
        *(us4*)(PbA + lr * 128 + ((kt * 32 + g * 8) ^ swzl)) = pk;
      }
      float oc[4];
      #pragma unroll
      for (int r = 0; r < 4; ++r) oc[r] = __shfl(corr, g * 4 + r);
      #pragma unroll
      for (int dt = 0; dt < 4; ++dt)
        #pragma unroll
        for (int r = 0; r < 4; ++r) oA[dt][r] *= oc[r];
    }
    // ---- online softmax + P write, set B ----
    {
      float mx = -INFINITY;
      #pragma unroll
      for (int kt = 0; kt < 4; ++kt)
        #pragma unroll
        for (int r = 0; r < 4; ++r) mx = fmaxf(mx, sB[kt][r]);
      mx = fmaxf(mx, __shfl_xor(mx, 16));
      mx = fmaxf(mx, __shfl_xor(mx, 32));
      const float mn = fmaxf(mB, mx);
      const float corr = __expf(mB - mn);
      float sum = 0.f;
      #pragma unroll
      for (int kt = 0; kt < 4; ++kt)
        #pragma unroll
        for (int r = 0; r < 4; ++r){
          const float pp = __expf(sB[kt][r] - mn);
          sB[kt][r] = pp; sum += pp;
        }
      sum += __shfl_xor(sum, 16);
      sum += __shfl_xor(sum, 32);
      lB = lB * corr + sum; mB = mn;
      #pragma unroll
      for (int kt = 0; kt < 4; ++kt){
        us4 pk;
        #pragma unroll
        for (int r = 0; r < 4; ++r) pk[r] = f2bf(sB[kt][r]);
        *(us4*)(PbB + lr * 128 + ((kt * 32 + g * 8) ^ swzl)) = pk;
      }
      float oc[4];
      #pragma unroll
      for (int r = 0; r < 4; ++r) oc[r] = __shfl(corr, g * 4 + r);
      #pragma unroll
      for (int dt = 0; dt < 4; ++dt)
        #pragma unroll
        for (int r = 0; r < 4; ++r) oB[dt][r] *= oc[r];
    }

    // ---- PV: A = P (LDS), B = V^T tile (LDS, read once per set pair) ----
    const short8 paA0 = *(const short8*)(PbA + lr * 128 + ((g * 16) ^ swzl));
    const short8 paA1 = *(const short8*)(PbA + lr * 128 + ((64 + g * 16) ^ swzl));
    const short8 paB0 = *(const short8*)(PbB + lr * 128 + ((g * 16) ^ swzl));
    const short8 paB1 = *(const short8*)(PbB + lr * 128 + ((64 + g * 16) ^ swzl));
    __builtin_amdgcn_s_setprio(1);
    #pragma unroll
    for (int dt = 0; dt < 4; ++dt){
      const int row = dt * 16 + lr;
      const int ro = row * 128, sw = (row & 7) << 4;
      const short8 vf0 = *(const short8*)(Vl[p] + ro + ((g * 16) ^ sw));
      const short8 vf1 = *(const short8*)(Vl[p] + ro + ((64 + g * 16) ^ sw));
      oA[dt] = __builtin_amdgcn_mfma_f32_16x16x32_bf16(paA0, vf0, oA[dt], 0, 0, 0);
      oA[dt] = __builtin_amdgcn_mfma_f32_16x16x32_bf16(paA1, vf1, oA[dt], 0, 0, 0);
      oB[dt] = __builtin_amdgcn_mfma_f32_16x16x32_bf16(paB0, vf0, oB[dt], 0, 0, 0);
      oB[dt] = __builtin_amdgcn_mfma_f32_16x16x32_bf16(paB1, vf1, oB[dt], 0, 0, 0);
    }
    __builtin_amdgcn_s_setprio(0);
  }

  // ---- finalize both sets: divide by l, store [B,T,C] fp32 ----
  const int b = bh >> 4, hh = bh & 15;
  {
    float lv[4];
    #pragma unroll
    for (int r = 0; r < 4; ++r) lv[r] = __shfl(lA, g * 4 + r);
    #pragma unroll
    for (int dt = 0; dt < 4; ++dt)
      #pragma unroll
      for (int r = 0; r < 4; ++r)
        Op[((size_t)(b * SEQ) + q0w + g * 4 + r) * D_MODEL + hh * 64 + dt * 16 + lr] = oA[dt][r] / lv[r];
  }
  {
    float lv[4];
    #pragma unroll
    for (int r = 0; r < 4; ++r) lv[r] = __shfl(lB, g * 4 + r);
    #pragma unroll
    for (int dt = 0; dt < 4; ++dt)
      #pragma unroll
      for (int r = 0; r < 4; ++r)
        Op[((size_t)(b * SEQ) + q0w + 16 + g * 4 + r) * D_MODEL + hh * 64 + dt * 16 + lr] = oB[dt][r] / lv[r];
  }
}

// ---------------- fused residual + layernorm ----------------
__global__ __launch_bounds__(256) void ln_kernel(const float* __restrict__ A,
                                                 const float* __restrict__ Badd,
                                                 const float* __restrict__ g,
                                                 const float* __restrict__ be,
                                                 float* __restrict__ outF,
                                                 unsigned short* __restrict__ outH){
  const int row = blockIdx.x, tid = threadIdx.x;
  const size_t base = (size_t)row * D_MODEL + tid * 4;
  float4 va = *(const float4*)(A + base);
  float4 vb = *(const float4*)(Badd + base);
  const float v0 = va.x + vb.x, v1 = va.y + vb.y, v2 = va.z + vb.z, v3 = va.w + vb.w;
  float s  = v0 + v1 + v2 + v3;
  float ss = v0*v0 + v1*v1 + v2*v2 + v3*v3;
  s = wave_sum(s); ss = wave_sum(ss);
  __shared__ float red[8];
  const int w = tid >> 6, lane = tid & 63;
  if (!lane){ red[w] = s; red[4 + w] = ss; }
  __syncthreads();
  s  = red[0] + red[1] + red[2] + red[3];
  ss = red[4] + red[5] + red[6] + red[7];
  const float mu  = s * (1.0f / D_MODEL);
  const float var = ss * (1.0f / D_MODEL) - mu * mu;
  const float rstd = rsqrtf(var + 1e-5f);
  float4 gg = *(const float4*)(g  + tid * 4);
  float4 bb = *(const float4*)(be + tid * 4);
  const float r0 = (v0 - mu) * rstd * gg.x + bb.x;
  const float r1 = (v1 - mu) * rstd * gg.y + bb.y;
  const float r2 = (v2 - mu) * rstd * gg.z + bb.z;
  const float r3 = (v3 - mu) * rstd * gg.w + bb.w;
  float4 of; of.x = r0; of.y = r1; of.z = r2; of.w = r3;
  *(float4*)(outF + base) = of;
  if (outH){
    us4 oh; oh[0] = f2bf(r0); oh[1] = f2bf(r1); oh[2] = f2bf(r2); oh[3] = f2bf(r3);
    *(us4*)(outH + base) = oh;
  }
}

extern "C" void kernel_launch(void* const* d_in, const int* in_sizes, int n_in,
                              void* d_out, int out_size, void* d_ws, size_t ws_size,
                              hipStream_t stream){
  (void)in_sizes; (void)n_in; (void)out_size; (void)ws_size;
  const float* x     = (const float*)d_in[0];
  const float* W_qkv = (const float*)d_in[1];
  const float* b_qkv = (const float*)d_in[2];
  const float* W1    = (const float*)d_in[3];
  const float* b1    = (const float*)d_in[4];
  const float* W2    = (const float*)d_in[5];
  const float* b2    = (const float*)d_in[6];
  const float* ln1g  = (const float*)d_in[7];
  const float* ln1b  = (const float*)d_in[8];
  const float* ln2g  = (const float*)d_in[9];
  const float* ln2b  = (const float*)d_in[10];

  char* ws = (char*)d_ws;
  const size_t MB = 1024ull * 1024ull;
  unsigned short* WqkvT = (unsigned short*)(ws + 0 * MB);   // [3072][1024] bf16, 6MB
  unsigned short* W1T   = (unsigned short*)(ws + 6 * MB);   // [4096][1024] bf16, 8MB
  unsigned short* W2T   = (unsigned short*)(ws + 14 * MB);  // [1024][4096] bf16, 8MB
  unsigned short* xbf   = (unsigned short*)(ws + 22 * MB);  // [4096][1024] bf16, 8MB
  unsigned short* qB    = (unsigned short*)(ws + 30 * MB);  // [B,H,T,64] bf16 (pre-scaled), 8.4MB
  unsigned short* kB    = (unsigned short*)(ws + 39 * MB);  // [B,H,T,64] bf16, 8.4MB
  unsigned short* vT    = (unsigned short*)(ws + 48 * MB);  // [B,H,64,T] bf16, 8.4MB
  float* attn = (float*)(ws + 57 * MB);                     // [B,T,C] f32, 16MB
  float* hF           = (float*)(ws + 30 * MB);             // reuse qB/kB region after attention
  unsigned short* hB  = (unsigned short*)(ws + 46 * MB);    // 8MB (dead kB/vT region)
  unsigned short* ff1 = (unsigned short*)(ws + 54 * MB);    // [4096][4096] bf16, 32MB (dead vT/attn)
  float* ff2          = (float*)(ws + 86 * MB);             // [4096][1024] f32, 16MB

  // 1. preprocess: casts + weight transposes
  cast_bf16_kernel<<<4096, 256, 0, stream>>>(x, xbf, ROWS * D_MODEL / 4);
  transpose_cast_kernel<<<dim3(96, 32), 256, 0, stream>>>(W_qkv, WqkvT, 1024, 3072);
  transpose_cast_kernel<<<dim3(128, 32), 256, 0, stream>>>(W1, W1T, 1024, 4096);
  transpose_cast_kernel<<<dim3(32, 128), 256, 0, stream>>>(W2, W2T, 4096, 1024);

  // 2. QKV projection -> qB (scaled), kB, vT (all bf16)
  gemm_kernel<0><<<dim3(3072 / 128, ROWS / 128), 256, 0, stream>>>(
      xbf, WqkvT, b_qkv, ROWS, 3072, 1024, nullptr, nullptr, qB, kB, vT);

  // 3. causal MFMA flash attention -> attn [B,T,C] fp32
  attn_mfma_kernel<<<512, 256, 0, stream>>>(qB, kB, vT, attn);

  // 4. h = LN(x + attn) -> hF fp32, hB bf16
  ln_kernel<<<ROWS, 256, 0, stream>>>(x, attn, ln1g, ln1b, hF, hB);

  // 5. ff1 = relu(h @ W1 + b1) -> bf16
  gemm_kernel<1><<<dim3(FFDIM / 128, ROWS / 128), 256, 0, stream>>>(
      hB, W1T, b1, ROWS, FFDIM, 1024, nullptr, ff1, nullptr, nullptr, nullptr);

  // 6. ff2 = ff1 @ W2 + b2 -> fp32
  gemm_kernel<2><<<dim3(1024 / 128, ROWS / 128), 256, 0, stream>>>(
      ff1, W2T, b2, ROWS, 1024, FFDIM, ff2, nullptr, nullptr, nullptr, nullptr);

  // 7. out = LN(h + ff2)
  ln_kernel<<<ROWS, 256, 0, stream>>>(hF, ff2, ln2g, ln2b, (float*)d_out, nullptr);
}

// Round 6
// 239.750 us; speedup vs baseline: 7.2989x; 1.1826x over previous
//
#include <hip/hip_runtime.h>

#define D_MODEL 1024
#define HEADS   16
#define HEAD_DIM 64
#define SEQ     2048
#define BATCH   2
#define ROWS    (BATCH*SEQ)   /* 4096 */
#define FFDIM   4096

typedef __attribute__((ext_vector_type(8))) short short8;
typedef __attribute__((ext_vector_type(4))) float f32x4;
typedef __attribute__((ext_vector_type(4))) unsigned short us4;

typedef const __attribute__((address_space(1))) unsigned int* gptr_t;
typedef __attribute__((address_space(3))) unsigned int* lptr_t;

__device__ __forceinline__ unsigned short f2bf(float f){
  unsigned int x = __float_as_uint(f);
  x += 0x7fffu + ((x >> 16) & 1u);
  return (unsigned short)(x >> 16);
}

__device__ __forceinline__ float wave_sum(float x){
  #pragma unroll
  for (int off = 32; off; off >>= 1) x += __shfl_xor(x, off);
  return x;
}

// ---------------- cast fp32 -> bf16 (vectorized) ----------------
__global__ __launch_bounds__(256) void cast_bf16_kernel(const float* __restrict__ in,
                                                        unsigned short* __restrict__ out, int n4){
  int i = blockIdx.x * 256 + threadIdx.x;
  if (i >= n4) return;
  float4 v = *(const float4*)(in + (size_t)i * 4);
  us4 o;
  o[0] = f2bf(v.x); o[1] = f2bf(v.y); o[2] = f2bf(v.z); o[3] = f2bf(v.w);
  *(us4*)(out + (size_t)i * 4) = o;
}

// ---------------- transpose + cast: in [R][C] f32 -> out [C][R] bf16 ----------------
__global__ __launch_bounds__(256) void transpose_cast_kernel(const float* __restrict__ in,
                                                             unsigned short* __restrict__ out,
                                                             int R, int C){
  __shared__ float tile[32][33];
  const int bc = blockIdx.x * 32, br = blockIdx.y * 32;
  const int tx = threadIdx.x & 31, ty = threadIdx.x >> 5;  // ty 0..7
  #pragma unroll
  for (int j = 0; j < 4; ++j)
    tile[ty + 8*j][tx] = in[(size_t)(br + ty + 8*j) * C + bc + tx];
  __syncthreads();
  #pragma unroll
  for (int j = 0; j < 4; ++j)
    out[(size_t)(bc + ty + 8*j) * R + br + tx] = f2bf(tile[tx][ty + 8*j]);
}

// ---------------- bf16 MFMA GEMM v2: 2-phase double-buffered, XCD-swizzled ----------------
// C[M,N] = A[M,K(chunk)] * BT[N,K]^T (+bias). Flat 1-D grid = gx*gy*nsplit, %8==0.
// EPI 0: QKV epilogue -> q bf16(scaled) [B,H,T,64], k bf16, V^T bf16 [B,H,64,T]
// EPI 1: relu -> bf16 row-major
// EPI 3: f32 partial (no bias) to outF + sk*M*N   (split-K)
template<int EPI>
__global__ __launch_bounds__(256) void gemm_kernel(const unsigned short* __restrict__ A,
                                                   const unsigned short* __restrict__ BT,
                                                   const float* __restrict__ bias,
                                                   int M, int N, int K, int kchunk,
                                                   int gx, int gy,
                                                   float* __restrict__ outF,
                                                   unsigned short* __restrict__ outH,
                                                   unsigned short* __restrict__ qo,
                                                   unsigned short* __restrict__ ko,
                                                   unsigned short* __restrict__ vT){
  __shared__ __align__(16) unsigned short Alds[2][128 * 32];
  __shared__ __align__(16) unsigned short Blds[2][128 * 32];
  const int tid = threadIdx.x;
  const int lane = tid & 63;
  const int wid = tid >> 6;
  const int wr = wid >> 1, wc = wid & 1;
  const int lrow = lane & 15, lgrp = lane >> 4;

  // XCD-aware bijective swizzle (nwg % 8 == 0 at every call site)
  const int nwg = gridDim.x;
  const int cpx = nwg >> 3;
  const int wg = (blockIdx.x & 7) * cpx + (blockIdx.x >> 3);
  const int nx = wg % gx;
  const int rest = wg / gx;
  const int my = rest % gy;
  const int sk = rest / gy;

  const int m0 = my * 128, n0 = nx * 128;
  const int kbase0 = sk * kchunk;

  const int sr = lane >> 2, sc = (lane & 3) * 8;

  f32x4 acc[4][4];
  #pragma unroll
  for (int i = 0; i < 4; ++i)
    #pragma unroll
    for (int j = 0; j < 4; ++j)
      acc[i][j] = f32x4{0.f, 0.f, 0.f, 0.f};

  // prologue: stage K-tile 0 into buffer 0
  #pragma unroll
  for (int it = 0; it < 2; ++it){
    const int c = wid * 2 + it;
    const int r = c * 16 + sr;
    __builtin_amdgcn_global_load_lds(
        (gptr_t)(const void*)(A + (size_t)(m0 + r) * K + kbase0 + sc),
        (lptr_t)(void*)(&Alds[0][c * 512]), 16, 0, 0);
    __builtin_amdgcn_global_load_lds(
        (gptr_t)(const void*)(BT + (size_t)(n0 + r) * K + kbase0 + sc),
        (lptr_t)(void*)(&Blds[0][c * 512]), 16, 0, 0);
  }

  const int nk = kchunk >> 5;
  int cur = 0;
  for (int kt = 0; kt < nk; ++kt){
    __syncthreads();   // drains the stage issued last iteration (or prologue)

    // issue next-tile stage early: latency hides under this tile's ds_read+MFMA
    if (kt + 1 < nk){
      const int kb = kbase0 + (kt + 1) * 32;
      #pragma unroll
      for (int it = 0; it < 2; ++it){
        const int c = wid * 2 + it;
        const int r = c * 16 + sr;
        __builtin_amdgcn_global_load_lds(
            (gptr_t)(const void*)(A + (size_t)(m0 + r) * K + kb + sc),
            (lptr_t)(void*)(&Alds[cur ^ 1][c * 512]), 16, 0, 0);
        __builtin_amdgcn_global_load_lds(
            (gptr_t)(const void*)(BT + (size_t)(n0 + r) * K + kb + sc),
            (lptr_t)(void*)(&Blds[cur ^ 1][c * 512]), 16, 0, 0);
      }
    }

    short8 af[4], bfr[4];
    #pragma unroll
    for (int f = 0; f < 4; ++f){
      af[f]  = *(const short8*)&Alds[cur][(wr * 64 + f * 16 + lrow) * 32 + lgrp * 8];
      bfr[f] = *(const short8*)&Blds[cur][(wc * 64 + f * 16 + lrow) * 32 + lgrp * 8];
    }
    __builtin_amdgcn_s_setprio(1);
    #pragma unroll
    for (int i = 0; i < 4; ++i)
      #pragma unroll
      for (int j = 0; j < 4; ++j)
        acc[i][j] = __builtin_amdgcn_mfma_f32_16x16x32_bf16(af[i], bfr[j], acc[i][j], 0, 0, 0);
    __builtin_amdgcn_s_setprio(0);
    cur ^= 1;
  }

  // epilogue: D row = (lane>>4)*4 + reg, col = lane&15 (m89-verified layout)
  float* const outP = (EPI == 3) ? outF + (size_t)sk * M * N : outF;
  #pragma unroll
  for (int i = 0; i < 4; ++i){
    const int rg = m0 + wr * 64 + i * 16 + lgrp * 4;   // multiple of 4
    #pragma unroll
    for (int j = 0; j < 4; ++j){
      const int cg = n0 + wc * 64 + j * 16 + lrow;
      const float bb = (EPI == 3) ? 0.f : bias[cg];
      if constexpr (EPI == 0){
        const int which = cg >> 10, rem = cg & 1023;
        const int hh = rem >> 6, dd = rem & 63;
        const int bb_ = rg >> 11, tt = rg & 2047;
        const size_t bh = (size_t)(bb_ * HEADS + hh);
        if (which == 2){
          us4 pk;
          #pragma unroll
          for (int r = 0; r < 4; ++r) pk[r] = f2bf(acc[i][j][r] + bb);
          *(us4*)(vT + (bh * 64 + dd) * SEQ + tt) = pk;
        } else {
          unsigned short* dst = which ? ko : qo;
          const float sc2 = which ? 1.0f : 0.125f;
          #pragma unroll
          for (int r = 0; r < 4; ++r)
            dst[(bh * SEQ + tt + r) * 64 + dd] = f2bf((acc[i][j][r] + bb) * sc2);
        }
      } else if constexpr (EPI == 1){
        #pragma unroll
        for (int r = 0; r < 4; ++r)
          outH[(size_t)(rg + r) * N + cg] = f2bf(fmaxf(acc[i][j][r] + bb, 0.f));
      } else {
        #pragma unroll
        for (int r = 0; r < 4; ++r)
          outP[(size_t)(rg + r) * N + cg] = acc[i][j][r] + bb;
      }
    }
  }
}

// ---------------- MFMA flash attention v2: LDS-shared K/V tiles, causal ----------------
__global__ __launch_bounds__(256) void attn_mfma_kernel(const unsigned short* __restrict__ Qb,
                                                        const unsigned short* __restrict__ Kb,
                                                        const unsigned short* __restrict__ VT,
                                                        float* __restrict__ Op){
  __shared__ __align__(16) char Kl[2][8192];
  __shared__ __align__(16) char Vl[2][8192];
  __shared__ __align__(16) char Pl[4][4096];
  const int tid = threadIdx.x;
  const int w = tid >> 6, lane = tid & 63;
  const int lr = lane & 15, g = lane >> 4;

  const int bx = blockIdx.x, u = bx & 255, half = bx >> 8;
  const int g8 = u >> 5;
  const int qg = half ? g8 : 15 - g8;
  const int bh = u & 31;

  const int q0w = qg * 128 + w * 32;
  const int qA = q0w + lr, qB = qA + 16;

  const char* const KbB = (const char*)(Kb + (size_t)bh * SEQ * 64);
  const char* const VbB = (const char*)(VT + (size_t)bh * 64 * SEQ);
  char* const PbA = Pl[w];
  char* const PbB = Pl[w] + 2048;

  const unsigned short* qra = Qb + ((size_t)bh * SEQ + qA) * 64 + g * 8;
  const short8 qfA0 = *(const short8*)(qra);
  const short8 qfA1 = *(const short8*)(qra + 32);
  const short8 qfB0 = *(const short8*)(qra + 16 * 64);
  const short8 qfB1 = *(const short8*)(qra + 16 * 64 + 32);

  f32x4 oA[4], oB[4];
  #pragma unroll
  for (int dt = 0; dt < 4; ++dt){ oA[dt] = f32x4{0.f,0.f,0.f,0.f}; oB[dt] = f32x4{0.f,0.f,0.f,0.f}; }
  float mA = -INFINITY, lA = 0.f, mB = -INFINITY, lB = 0.f;
  const int swzl = (lr & 7) << 4;

  const int kbmax = 2 * qg + 1;

  short8 st[4];
  {
    #pragma unroll
    for (int c = 0; c < 2; ++c){
      const int L = c * 4096 + tid * 16;
      st[c] = *(const short8*)(KbB + L);
      const int row = L >> 7, col = L & 127;
      st[2 + c] = *(const short8*)(VbB + (size_t)row * 4096 + col);
    }
  }

  for (int kb = 0; kb <= kbmax; ++kb){
    const int p = kb & 1;
    const int k0 = kb * 64;

    #pragma unroll
    for (int c = 0; c < 2; ++c){
      const int L = c * 4096 + tid * 16;
      const int row = L >> 7, col = L & 127;
      const int dst = row * 128 + (col ^ ((row & 7) << 4));
      *(short8*)(Kl[p] + dst) = st[c];
      *(short8*)(Vl[p] + dst) = st[2 + c];
    }
    __syncthreads();

    if (kb < kbmax){
      #pragma unroll
      for (int c = 0; c < 2; ++c){
        const int L = c * 4096 + tid * 16;
        st[c] = *(const short8*)(KbB + (size_t)(kb + 1) * 8192 + L);
        const int row = L >> 7, col = L & 127;
        st[2 + c] = *(const short8*)(VbB + (size_t)row * 4096 + (size_t)(kb + 1) * 128 + col);
      }
    }

    f32x4 sA[4], sB[4];
    __builtin_amdgcn_s_setprio(1);
    #pragma unroll
    for (int kt = 0; kt < 4; ++kt){
      const int row = kt * 16 + lr;
      const int ro = row * 128, sw = (row & 7) << 4;
      const short8 kf0 = *(const short8*)(Kl[p] + ro + ((g * 16) ^ sw));
      const short8 kf1 = *(const short8*)(Kl[p] + ro + ((64 + g * 16) ^ sw));
      sA[kt] = __builtin_amdgcn_mfma_f32_16x16x32_bf16(kf0, qfA0, f32x4{0.f,0.f,0.f,0.f}, 0, 0, 0);
      sA[kt] = __builtin_amdgcn_mfma_f32_16x16x32_bf16(kf1, qfA1, sA[kt], 0, 0, 0);
      sB[kt] = __builtin_amdgcn_mfma_f32_16x16x32_bf16(kf0, qfB0, f32x4{0.f,0.f,0.f,0.f}, 0, 0, 0);
      sB[kt] = __builtin_amdgcn_mfma_f32_16x16x32_bf16(kf1, qfB1, sB[kt], 0, 0, 0);
    }
    __builtin_amdgcn_s_setprio(0);

    if (kb >= kbmax - 1){
      #pragma unroll
      for (int kt = 0; kt < 4; ++kt)
        #pragma unroll
        for (int r = 0; r < 4; ++r){
          const int key = k0 + kt * 16 + g * 4 + r;
          if (key > qA) sA[kt][r] = -INFINITY;
          if (key > qB) sB[kt][r] = -INFINITY;
        }
    }

    {
      float mx = -INFINITY;
      #pragma unroll
      for (int kt = 0; kt < 4; ++kt)
        #pragma unroll
        for (int r = 0; r < 4; ++r) mx = fmaxf(mx, sA[kt][r]);
      mx = fmaxf(mx, __shfl_xor(mx, 16));
      mx = fmaxf(mx, __shfl_xor(mx, 32));
      const float mn = fmaxf(mA, mx);
      const float corr = __expf(mA - mn);
      float sum = 0.f;
      #pragma unroll
      for (int kt = 0; kt < 4; ++kt)
        #pragma unroll
        for (int r = 0; r < 4; ++r){
          const float pp = __expf(sA[kt][r] - mn);
          sA[kt][r] = pp; sum += pp;
        }
      sum += __shfl_xor(sum, 16);
      sum += __shfl_xor(sum, 32);
      lA = lA * corr + sum; mA = mn;
      #pragma unroll
      for (int kt = 0; kt < 4; ++kt){
        us4 pk;
        #pragma unroll
        for (int r = 0; r < 4; ++r) pk[r] = f2bf(sA[kt][r]);
        *(us4*)(PbA + lr * 128 + ((kt * 32 + g * 8) ^ swzl)) = pk;
      }
      float oc[4];
      #pragma unroll
      for (int r = 0; r < 4; ++r) oc[r] = __shfl(corr, g * 4 + r);
      #pragma unroll
      for (int dt = 0; dt < 4; ++dt)
        #pragma unroll
        for (int r = 0; r < 4; ++r) oA[dt][r] *= oc[r];
    }
    {
      float mx = -INFINITY;
      #pragma unroll
      for (int kt = 0; kt < 4; ++kt)
        #pragma unroll
        for (int r = 0; r < 4; ++r) mx = fmaxf(mx, sB[kt][r]);
      mx = fmaxf(mx, __shfl_xor(mx, 16));
      mx = fmaxf(mx, __shfl_xor(mx, 32));
      const float mn = fmaxf(mB, mx);
      const float corr = __expf(mB - mn);
      float sum = 0.f;
      #pragma unroll
      for (int kt = 0; kt < 4; ++kt)
        #pragma unroll
        for (int r = 0; r < 4; ++r){
          const float pp = __expf(sB[kt][r] - mn);
          sB[kt][r] = pp; sum += pp;
        }
      sum += __shfl_xor(sum, 16);
      sum += __shfl_xor(sum, 32);
      lB = lB * corr + sum; mB = mn;
      #pragma unroll
      for (int kt = 0; kt < 4; ++kt){
        us4 pk;
        #pragma unroll
        for (int r = 0; r < 4; ++r) pk[r] = f2bf(sB[kt][r]);
        *(us4*)(PbB + lr * 128 + ((kt * 32 + g * 8) ^ swzl)) = pk;
      }
      float oc[4];
      #pragma unroll
      for (int r = 0; r < 4; ++r) oc[r] = __shfl(corr, g * 4 + r);
      #pragma unroll
      for (int dt = 0; dt < 4; ++dt)
        #pragma unroll
        for (int r = 0; r < 4; ++r) oB[dt][r] *= oc[r];
    }

    const short8 paA0 = *(const short8*)(PbA + lr * 128 + ((g * 16) ^ swzl));
    const short8 paA1 = *(const short8*)(PbA + lr * 128 + ((64 + g * 16) ^ swzl));
    const short8 paB0 = *(const short8*)(PbB + lr * 128 + ((g * 16) ^ swzl));
    const short8 paB1 = *(const short8*)(PbB + lr * 128 + ((64 + g * 16) ^ swzl));
    __builtin_amdgcn_s_setprio(1);
    #pragma unroll
    for (int dt = 0; dt < 4; ++dt){
      const int row = dt * 16 + lr;
      const int ro = row * 128, sw = (row & 7) << 4;
      const short8 vf0 = *(const short8*)(Vl[p] + ro + ((g * 16) ^ sw));
      const short8 vf1 = *(const short8*)(Vl[p] + ro + ((64 + g * 16) ^ sw));
      oA[dt] = __builtin_amdgcn_mfma_f32_16x16x32_bf16(paA0, vf0, oA[dt], 0, 0, 0);
      oA[dt] = __builtin_amdgcn_mfma_f32_16x16x32_bf16(paA1, vf1, oA[dt], 0, 0, 0);
      oB[dt] = __builtin_amdgcn_mfma_f32_16x16x32_bf16(paB0, vf0, oB[dt], 0, 0, 0);
      oB[dt] = __builtin_amdgcn_mfma_f32_16x16x32_bf16(paB1, vf1, oB[dt], 0, 0, 0);
    }
    __builtin_amdgcn_s_setprio(0);
  }

  const int b = bh >> 4, hh = bh & 15;
  {
    float lv[4];
    #pragma unroll
    for (int r = 0; r < 4; ++r) lv[r] = __shfl(lA, g * 4 + r);
    #pragma unroll
    for (int dt = 0; dt < 4; ++dt)
      #pragma unroll
      for (int r = 0; r < 4; ++r)
        Op[((size_t)(b * SEQ) + q0w + g * 4 + r) * D_MODEL + hh * 64 + dt * 16 + lr] = oA[dt][r] / lv[r];
  }
  {
    float lv[4];
    #pragma unroll
    for (int r = 0; r < 4; ++r) lv[r] = __shfl(lB, g * 4 + r);
    #pragma unroll
    for (int dt = 0; dt < 4; ++dt)
      #pragma unroll
      for (int r = 0; r < 4; ++r)
        Op[((size_t)(b * SEQ) + q0w + 16 + g * 4 + r) * D_MODEL + hh * 64 + dt * 16 + lr] = oB[dt][r] / lv[r];
  }
}

// ---------------- fused (residual + residual2 + bias) + layernorm ----------------
// v = A + B1 (+ B2) (+ bias); out = LN(v). B2/bias/outH nullable.
__global__ __launch_bounds__(256) void ln_kernel(const float* __restrict__ A,
                                                 const float* __restrict__ B1,
                                                 const float* __restrict__ B2,
                                                 const float* __restrict__ bias,
                                                 const float* __restrict__ g,
                                                 const float* __restrict__ be,
                                                 float* __restrict__ outF,
                                                 unsigned short* __restrict__ outH){
  const int row = blockIdx.x, tid = threadIdx.x;
  const size_t base = (size_t)row * D_MODEL + tid * 4;
  float4 va = *(const float4*)(A + base);
  float4 vb = *(const float4*)(B1 + base);
  float v0 = va.x + vb.x, v1 = va.y + vb.y, v2 = va.z + vb.z, v3 = va.w + vb.w;
  if (B2){
    float4 vc = *(const float4*)(B2 + base);
    v0 += vc.x; v1 += vc.y; v2 += vc.z; v3 += vc.w;
  }
  if (bias){
    float4 vd = *(const float4*)(bias + tid * 4);
    v0 += vd.x; v1 += vd.y; v2 += vd.z; v3 += vd.w;
  }
  float s  = v0 + v1 + v2 + v3;
  float ss = v0*v0 + v1*v1 + v2*v2 + v3*v3;
  s = wave_sum(s); ss = wave_sum(ss);
  __shared__ float red[8];
  const int w = tid >> 6, lane = tid & 63;
  if (!lane){ red[w] = s; red[4 + w] = ss; }
  __syncthreads();
  s  = red[0] + red[1] + red[2] + red[3];
  ss = red[4] + red[5] + red[6] + red[7];
  const float mu  = s * (1.0f / D_MODEL);
  const float var = ss * (1.0f / D_MODEL) - mu * mu;
  const float rstd = rsqrtf(var + 1e-5f);
  float4 gg = *(const float4*)(g  + tid * 4);
  float4 bb = *(const float4*)(be + tid * 4);
  const float r0 = (v0 - mu) * rstd * gg.x + bb.x;
  const float r1 = (v1 - mu) * rstd * gg.y + bb.y;
  const float r2 = (v2 - mu) * rstd * gg.z + bb.z;
  const float r3 = (v3 - mu) * rstd * gg.w + bb.w;
  float4 of; of.x = r0; of.y = r1; of.z = r2; of.w = r3;
  *(float4*)(outF + base) = of;
  if (outH){
    us4 oh; oh[0] = f2bf(r0); oh[1] = f2bf(r1); oh[2] = f2bf(r2); oh[3] = f2bf(r3);
    *(us4*)(outH + base) = oh;
  }
}

extern "C" void kernel_launch(void* const* d_in, const int* in_sizes, int n_in,
                              void* d_out, int out_size, void* d_ws, size_t ws_size,
                              hipStream_t stream){
  (void)in_sizes; (void)n_in; (void)out_size;
  const float* x     = (const float*)d_in[0];
  const float* W_qkv = (const float*)d_in[1];
  const float* b_qkv = (const float*)d_in[2];
  const float* W1    = (const float*)d_in[3];
  const float* b1    = (const float*)d_in[4];
  const float* W2    = (const float*)d_in[5];
  const float* b2    = (const float*)d_in[6];
  const float* ln1g  = (const float*)d_in[7];
  const float* ln1b  = (const float*)d_in[8];
  const float* ln2g  = (const float*)d_in[9];
  const float* ln2b  = (const float*)d_in[10];

  char* ws = (char*)d_ws;
  const size_t MB = 1024ull * 1024ull;
  unsigned short* WqkvT = (unsigned short*)(ws + 0 * MB);   // [3072][1024] bf16, 6MB (dead after QKV)
  unsigned short* W1T   = (unsigned short*)(ws + 6 * MB);   // [4096][1024] bf16, 8MB (dead after FFN1)
  unsigned short* W2T   = (unsigned short*)(ws + 14 * MB);  // [1024][4096] bf16, 8MB (dead after FFN2)
  unsigned short* xbf   = (unsigned short*)(ws + 22 * MB);  // 8MB (dead after QKV)
  unsigned short* qB    = (unsigned short*)(ws + 30 * MB);  // 8.4MB (dead after attn)
  unsigned short* kB    = (unsigned short*)(ws + 39 * MB);  // 8.4MB (dead after attn)
  unsigned short* vT    = (unsigned short*)(ws + 48 * MB);  // 8.4MB (dead after attn)
  float* attn = (float*)(ws + 57 * MB);                     // 16MB (dead after LN1)
  float* hF           = (float*)(ws + 30 * MB);             // 16MB, LN1->LN2 (over dead qB/kB)
  unsigned short* hB  = (unsigned short*)(ws + 46 * MB);    // 8MB, LN1->FFN1 (dead kB/vT)
  unsigned short* ff1 = (unsigned short*)(ws + 54 * MB);    // 32MB, FFN1->FFN2 (dead vT/attn)
  float* p0           = (float*)(ws + 86 * MB);             // 16MB partial 0, FFN2->LN2
  float* p1           = (float*)(ws + 102 * MB);            // 16MB partial 1 (only if ws allows)

  const int nsplit = (ws_size >= 119 * MB) ? 2 : 1;

  // 1. preprocess
  cast_bf16_kernel<<<4096, 256, 0, stream>>>(x, xbf, ROWS * D_MODEL / 4);
  transpose_cast_kernel<<<dim3(96, 32), 256, 0, stream>>>(W_qkv, WqkvT, 1024, 3072);
  transpose_cast_kernel<<<dim3(128, 32), 256, 0, stream>>>(W1, W1T, 1024, 4096);
  transpose_cast_kernel<<<dim3(32, 128), 256, 0, stream>>>(W2, W2T, 4096, 1024);

  // 2. QKV projection (M=4096,N=3072,K=1024): grid 24*32=768
  gemm_kernel<0><<<768, 256, 0, stream>>>(
      xbf, WqkvT, b_qkv, ROWS, 3072, 1024, 1024, 24, 32, nullptr, nullptr, qB, kB, vT);

  // 3. causal MFMA flash attention
  attn_mfma_kernel<<<512, 256, 0, stream>>>(qB, kB, vT, attn);

  // 4. h = LN(x + attn)
  ln_kernel<<<ROWS, 256, 0, stream>>>(x, attn, nullptr, nullptr, ln1g, ln1b, hF, hB);

  // 5. ff1 = relu(h @ W1 + b1) (M=4096,N=4096,K=1024): grid 32*32=1024
  gemm_kernel<1><<<1024, 256, 0, stream>>>(
      hB, W1T, b1, ROWS, FFDIM, 1024, 1024, 32, 32, nullptr, ff1, nullptr, nullptr, nullptr);

  // 6. ff2 partials = ff1 @ W2 (M=4096,N=1024,K=4096), split-K: grid 8*32*nsplit
  gemm_kernel<3><<<256 * nsplit, 256, 0, stream>>>(
      ff1, W2T, nullptr, ROWS, 1024, FFDIM, FFDIM / nsplit, 8, 32, p0, nullptr, nullptr, nullptr, nullptr);

  // 7. out = LN(h + p0 (+ p1) + b2)
  ln_kernel<<<ROWS, 256, 0, stream>>>(hF, p0, (nsplit == 2) ? p1 : nullptr, b2,
                                      ln2g, ln2b, (float*)d_out, nullptr);
}